// Round 8
// baseline (758.522 us; speedup 1.0000x reference)
//
#include <hip/hip_runtime.h>
#include <math.h>

// GAT pipeline. Layer2 collapsed algebraically: mean(GAT2) = (Σ_s w_s hnei[s])@W2^T
// with w_s = Σ_{e:src=s} α_e; s2 scores fused into gat1 epilogue via v2 = W2^T a2.
// bf16-packed z/hnei; no-max softmax; MFMA GEMM1 (split-A, LDS-staged B + score tile).

#define CAP 128   // per-wave LDS edge cache; deg>CAP falls back to recompute

typedef unsigned int  uint_t;
typedef unsigned short ushort_t;
typedef __attribute__((ext_vector_type(8))) short short8;
typedef __attribute__((ext_vector_type(4))) float floatx4;

__device__ __forceinline__ float wred_sum(float v){
#pragma unroll
  for (int o = 1; o < 64; o <<= 1) v += __shfl_xor(v, o, 64);
  return v;
}
__device__ __forceinline__ float lrelu(float x){ return x >= 0.f ? x : 0.01f*x; }
__device__ __forceinline__ ushort_t f2b(float f){
  uint_t u = __float_as_uint(f);
  u = (u + 0x7FFFu + ((u >> 16) & 1u)) >> 16;   // RNE
  return (ushort_t)u;
}
__device__ __forceinline__ float b2f_lo(uint_t w){ return __uint_as_float(w << 16); }
__device__ __forceinline__ float b2f_hi(uint_t w){ return __uint_as_float(w & 0xFFFF0000u); }

// ---------------- pack: W1 tiles (bx 0..127), layer1 score tile (bx 128),
// v2 = [W2^T a2_src ; W2^T a2_dst] f32 (bx 129)
__global__ void k_wpack(const float* __restrict__ W1, const float* __restrict__ W2,
                        const float* __restrict__ a1, const float* __restrict__ a2,
                        ushort_t* __restrict__ w1bp, float* __restrict__ v2){
  __shared__ float v[8][128];
  const int bx = blockIdx.x, t = threadIdx.x;
  if (bx < 128){
    int idx = bx*256 + t;
    int j = idx & 7, lane = (idx >> 3) & 63, ks = (idx >> 9) & 3, tt = idx >> 11;
    int n = tt*16 + (lane & 15), k = ks*32 + (lane >> 4)*8 + j;
    w1bp[idx] = f2b(W1[n*128 + k]);
  } else if (bx == 128){
    // layer1 score tile: col 0..3 = src score vec per head, 4..7 = dst
    for (int o = t; o < 1024; o += 256){
      int col = o >> 7, k = o & 127, hh = col & 3, off = (col >> 2)*64;
      float s = 0.f;
      for (int n = 0; n < 64; n++) s += a1[hh*128 + off + n] * W1[(hh*64 + n)*128 + k];
      v[col][k] = s;
    }
    __syncthreads();
    for (int idx = t; idx < 2048; idx += 256){
      int j = idx & 7, lane = (idx >> 3) & 63, ks = idx >> 9;
      int col = lane & 15, k = ks*32 + (lane >> 4)*8 + j;
      w1bp[32768 + idx] = (col < 8) ? f2b(v[col][k]) : (ushort_t)0;
    }
  } else {
    // v2[k] = sum_j W2[j][k]*a2[j]; v2[256+k] = sum_j W2[j][k]*a2[64+j]
    float s0 = 0.f, s1 = 0.f;
    for (int j = 0; j < 64; j++){
      float wjk = W2[j*256 + t];
      s0 += wjk * a2[j];
      s1 += wjk * a2[64 + j];
    }
    v2[t] = s0; v2[256 + t] = s1;
  }
}

// ---------------- GEMM1 (MFMA, split-A, LDS-staged B): zb + layer1 scores
__global__ __launch_bounds__(512) void k_gemm1m(const float* __restrict__ h,
    const ushort_t* __restrict__ w1bp,
    uint2* __restrict__ zb, float* __restrict__ s1s, float* __restrict__ s1d, int N)
{
  __shared__ __align__(16) ushort_t ldsB[34816];   // 69,632 B
  const int tid = threadIdx.x;
  {
    const uint4* src = (const uint4*)w1bp;
    uint4* dst = (uint4*)ldsB;
    for (int i = tid; i < 4352; i += 512) dst[i] = src[i];
  }
  __syncthreads();
  const int wave = tid >> 6, lane = tid & 63;
  const int quad = lane >> 4, l16 = lane & 15;
  const int row0 = blockIdx.x*128 + wave*16;
  if (row0 >= N) return;
  const int ar = (row0 + l16 < N) ? (row0 + l16) : (N - 1);   // clamp; dups discarded
  floatx4 c[17];
#pragma unroll
  for (int t = 0; t < 17; t++) c[t] = (floatx4){0.f,0.f,0.f,0.f};
#pragma unroll
  for (int ks = 0; ks < 4; ks++){
    const float* ap = &h[(size_t)ar*128 + ks*32 + quad*8];
    float4 v0 = *(const float4*)ap;
    float4 v1 = *(const float4*)(ap + 4);
    float vv[8] = {v0.x,v0.y,v0.z,v0.w,v1.x,v1.y,v1.z,v1.w};
    short8 ahi, alo;
#pragma unroll
    for (int j = 0; j < 8; j++){
      ushort_t hb = f2b(vv[j]);
      float hf = __uint_as_float((uint_t)hb << 16);
      ahi[j] = (short)hb;
      alo[j] = (short)f2b(vv[j] - hf);
    }
#pragma unroll
    for (int t = 0; t < 17; t++){
      short8 b = *(const short8*)&ldsB[(size_t)((t*4 + ks)*64 + lane)*8];
      c[t] = __builtin_amdgcn_mfma_f32_16x16x32_bf16(ahi, b, c[t], 0, 0, 0);
      c[t] = __builtin_amdgcn_mfma_f32_16x16x32_bf16(alo, b, c[t], 0, 0, 0);
    }
  }
#pragma unroll
  for (int i = 0; i < 4; i++){
    const int r = row0 + quad*4 + i;
    if (r >= N) continue;
#pragma unroll
    for (int m = 0; m < 4; m++){
      uint_t w0 = (uint_t)f2b(c[0*4+m][i]) | ((uint_t)f2b(c[1*4+m][i]) << 16);
      uint_t w1 = (uint_t)f2b(c[2*4+m][i]) | ((uint_t)f2b(c[3*4+m][i]) << 16);
      zb[(size_t)r*64 + m*16 + l16] = make_uint2(w0, w1);
    }
    const float sv = c[16][i];
    if (l16 < 4) s1s[r*4 + l16] = sv;
    else if (l16 < 8) s1d[r*4 + (l16 - 4)] = sv;
  }
}

// ---------------- CSR build (layer1 only)
__global__ void k_hist(const int* __restrict__ d, int* __restrict__ deg, int E){
  int i = blockIdx.x*256 + threadIdx.x;
  if (i < E) atomicAdd(&deg[d[i]], 1);
}
__global__ __launch_bounds__(256) void k_scan1(const int* __restrict__ deg, int* __restrict__ part){
  __shared__ int tmp[256];
  int t = threadIdx.x;
  tmp[t] = deg[blockIdx.x*256 + t];
  __syncthreads();
  for (int off = 128; off > 0; off >>= 1){
    if (t < off) tmp[t] += tmp[t+off];
    __syncthreads();
  }
  if (t == 0) part[blockIdx.x] = tmp[0];
}
__global__ __launch_bounds__(512) void k_scan2(int* __restrict__ part, int B){
  __shared__ int tmp[512];
  int t = threadIdx.x;
  int v = (t < B) ? part[t] : 0;
  tmp[t] = v; __syncthreads();
  for (int off = 1; off < 512; off <<= 1){
    int x = (t >= off) ? tmp[t-off] : 0;
    __syncthreads();
    tmp[t] += x;
    __syncthreads();
  }
  if (t < B) part[t] = tmp[t] - v;   // exclusive
}
__global__ __launch_bounds__(256) void k_scan3(const int* __restrict__ deg, const int* __restrict__ part,
    int* __restrict__ rowptr, int* __restrict__ cursor){
  __shared__ int tmp[256];
  int t = threadIdx.x, i = blockIdx.x*256 + t;
  int v = deg[i];
  tmp[t] = v; __syncthreads();
  for (int off = 1; off < 256; off <<= 1){
    int x = (t >= off) ? tmp[t-off] : 0;
    __syncthreads();
    tmp[t] += x;
    __syncthreads();
  }
  int excl = tmp[t] - v + part[blockIdx.x];
  rowptr[i] = excl; cursor[i] = excl;
}
__global__ void k_scatter(const int* __restrict__ s, const int* __restrict__ d,
    int* __restrict__ cursor, int* __restrict__ csr, int E){
  int i = blockIdx.x*256 + threadIdx.x;
  if (i < E){
    int p = atomicAdd(&cursor[d[i]], 1);
    csr[p] = s[i];
  }
}

// ---------------- layer1 GAT aggregation + ELU -> hneib bf16 + fused layer2 scores
__global__ __launch_bounds__(256) void k_gat1(
    const uint2* __restrict__ zb, const float* __restrict__ s1src, const float* __restrict__ s1dst,
    const int* __restrict__ rowptr, const int* __restrict__ csr, const float* __restrict__ v2,
    uint_t* __restrict__ hneib, float* __restrict__ s2s, float* __restrict__ s2d, int N)
{
  __shared__ int   sbuf[4][CAP];
  __shared__ __align__(16) float4 ebuf[4][CAP];
  __shared__ float v2s[512];
  const int tid = threadIdx.x;
  v2s[tid] = v2[tid];
  v2s[tid + 256] = v2[tid + 256];
  __syncthreads();
  const int wave = tid >> 6, lane = tid & 63;
  const int dst = blockIdx.x*4 + wave;
  if (dst >= N) return;
  const int beg = rowptr[dst];
  const int deg = rowptr[dst+1] - beg;
  const float4 sd = *(const float4*)&s1dst[dst*4];
  float t0=0.f,t1=0.f,t2=0.f,t3=0.f;
  for (int j = lane; j < deg; j += 64){
    int s = csr[beg+j];
    float4 sv = *(const float4*)&s1src[s*4];
    float4 a;
    a.x = __expf(lrelu(sv.x+sd.x)); a.y = __expf(lrelu(sv.y+sd.y));
    a.z = __expf(lrelu(sv.z+sd.z)); a.w = __expf(lrelu(sv.w+sd.w));
    if (j < CAP){ sbuf[wave][j] = s; ebuf[wave][j] = a; }
    t0 += a.x; t1 += a.y; t2 += a.z; t3 += a.w;
  }
  const float inv[4] = {1.f/wred_sum(t0), 1.f/wred_sum(t1), 1.f/wred_sum(t2), 1.f/wred_sum(t3)};
  const int eh = lane >> 5, li = lane & 31;
  float acc[2][4] = {};
  int jj = 0;
  if (deg <= CAP){
    for (; jj + 2 <= deg; jj += 2){
      const int j = jj + eh;
      int s = sbuf[wave][j]; float4 al = ebuf[wave][j];
      uint4 u = *((const uint4*)(zb + (size_t)s*64) + li);
      acc[0][0] += al.x * b2f_lo(u.x);
      acc[0][1] += al.y * b2f_hi(u.x);
      acc[0][2] += al.z * b2f_lo(u.y);
      acc[0][3] += al.w * b2f_hi(u.y);
      acc[1][0] += al.x * b2f_lo(u.z);
      acc[1][1] += al.y * b2f_hi(u.z);
      acc[1][2] += al.z * b2f_lo(u.w);
      acc[1][3] += al.w * b2f_hi(u.w);
    }
    if (jj < deg && eh == 0){
      int s = sbuf[wave][jj]; float4 al = ebuf[wave][jj];
      uint4 u = *((const uint4*)(zb + (size_t)s*64) + li);
      acc[0][0] += al.x * b2f_lo(u.x);
      acc[0][1] += al.y * b2f_hi(u.x);
      acc[0][2] += al.z * b2f_lo(u.y);
      acc[0][3] += al.w * b2f_hi(u.y);
      acc[1][0] += al.x * b2f_lo(u.z);
      acc[1][1] += al.y * b2f_hi(u.z);
      acc[1][2] += al.z * b2f_lo(u.w);
      acc[1][3] += al.w * b2f_hi(u.w);
    }
  } else {
    for (; jj < deg; jj += 2){
      const int j = jj + eh;
      const bool v = j < deg;
      const int jc = v ? j : jj;
      int s; float4 al;
      if (jc < CAP){ s = sbuf[wave][jc]; al = ebuf[wave][jc]; }
      else {
        s = csr[beg+jc];
        float4 sv = *(const float4*)&s1src[s*4];
        al.x = __expf(lrelu(sv.x+sd.x)); al.y = __expf(lrelu(sv.y+sd.y));
        al.z = __expf(lrelu(sv.z+sd.z)); al.w = __expf(lrelu(sv.w+sd.w));
      }
      if (!v){ al.x=0.f; al.y=0.f; al.z=0.f; al.w=0.f; }
      uint4 u = *((const uint4*)(zb + (size_t)s*64) + li);
      acc[0][0] += al.x * b2f_lo(u.x);
      acc[0][1] += al.y * b2f_hi(u.x);
      acc[0][2] += al.z * b2f_lo(u.y);
      acc[0][3] += al.w * b2f_hi(u.y);
      acc[1][0] += al.x * b2f_lo(u.z);
      acc[1][1] += al.y * b2f_hi(u.z);
      acc[1][2] += al.z * b2f_lo(u.w);
      acc[1][3] += al.w * b2f_hi(u.w);
    }
  }
  // combine parity halves: both halves end with identical sums
#pragma unroll
  for (int k = 0; k < 2; k++)
#pragma unroll
    for (int hh = 0; hh < 4; hh++) acc[k][hh] += __shfl_xor(acc[k][hh], 32, 64);
  // ELU (all lanes; dims hh*64+2li, +1) + fused s2 score dot (half0=src vec, half1=dst)
  const float* vv = &v2s[eh*256];
  float p = 0.f;
#pragma unroll
  for (int hh = 0; hh < 4; hh++){
    float e0 = acc[0][hh]*inv[hh]; e0 = e0 > 0.f ? e0 : expm1f(e0);
    float e1 = acc[1][hh]*inv[hh]; e1 = e1 > 0.f ? e1 : expm1f(e1);
    p += e0 * vv[hh*64 + 2*li] + e1 * vv[hh*64 + 2*li + 1];
    if (eh == 0)
      hneib[(size_t)dst*128 + hh*32 + li] = (uint_t)f2b(e0) | ((uint_t)f2b(e1) << 16);
  }
#pragma unroll
  for (int o = 1; o < 32; o <<= 1) p += __shfl_xor(p, o, 64);
  if (lane == 0)  s2s[dst] = p;
  if (lane == 32) s2d[dst] = p;
}

// ---------------- layer2 denominators: edge-parallel over original lists
__global__ void k_denom2(const int* __restrict__ srcI, const int* __restrict__ dstI,
    const float* __restrict__ s2s, const float* __restrict__ s2d,
    float* __restrict__ den, int E)
{
  int i = blockIdx.x*256 + threadIdx.x;
  if (i < E){
    int d = dstI[i];
    float e = __expf(lrelu(s2s[srcI[i]] + s2d[d]));
    atomicAdd(&den[d], e);
  }
}
// ---------------- layer2 source weights: w[s] = sum alpha over edges with src=s
__global__ void k_wsum(const int* __restrict__ srcI, const int* __restrict__ dstI,
    const float* __restrict__ s2s, const float* __restrict__ s2d,
    const float* __restrict__ den, float* __restrict__ wsrc, int E)
{
  int i = blockIdx.x*256 + threadIdx.x;
  if (i < E){
    int s = srcI[i], d = dstI[i];
    float e = __expf(lrelu(s2s[s] + s2d[d]));
    atomicAdd(&wsrc[s], e / den[d]);
  }
}
// ---------------- weighted hnei sum (coalesced): acc256[dim] = sum_n w[n]*hnei[n][dim]
__global__ __launch_bounds__(256) void k_hsum(const uint_t* __restrict__ hneib,
    const float* __restrict__ wsrc, float* __restrict__ acc256, int N)
{
  __shared__ float pr[512];
  const int t = threadIdx.x;
  const int h2 = t >> 7, p = t & 127;
  float a0 = 0.f, a1 = 0.f;
  const int step = gridDim.x * 2;
  for (int n = blockIdx.x*2 + h2; n < N; n += step){
    float wn = wsrc[n];
    uint_t u = hneib[(size_t)n*128 + p];
    a0 += wn * b2f_lo(u);
    a1 += wn * b2f_hi(u);
  }
  pr[h2*256 + 2*p]     = a0;
  pr[h2*256 + 2*p + 1] = a1;
  __syncthreads();
  float v = pr[t] + pr[256 + t];
  int pp = t >> 1;
  int d = (pp >> 5)*64 + 2*(pp & 31) + (t & 1);
  atomicAdd(&acc256[d], v);
}

// ---------------- fractal: accFrac[s*128+k] = sum_n h[fcm[n,s]][k]   (exact f32)
__global__ __launch_bounds__(256) void k_frac(const float* __restrict__ h,
    const int* __restrict__ fcm, float* __restrict__ accFrac, int N)
{
  __shared__ float red[4][6][64];
  const int wave = threadIdx.x >> 6, lane = threadIdx.x & 63;
  float a[6] = {0.f,0.f,0.f,0.f,0.f,0.f};
  const int stride = gridDim.x * 4;
  for (int n = blockIdx.x*4 + wave; n < N; n += stride){
    int i0 = fcm[n*3], i1 = fcm[n*3+1], i2 = fcm[n*3+2];
    a[0] += h[(size_t)i0*128 + lane]; a[1] += h[(size_t)i0*128 + 64 + lane];
    a[2] += h[(size_t)i1*128 + lane]; a[3] += h[(size_t)i1*128 + 64 + lane];
    a[4] += h[(size_t)i2*128 + lane]; a[5] += h[(size_t)i2*128 + 64 + lane];
  }
#pragma unroll
  for (int q = 0; q < 6; q++) red[wave][q][lane] = a[q];
  __syncthreads();
  if (wave == 0){
#pragma unroll
    for (int q = 0; q < 6; q++){
      float v = red[0][q][lane]+red[1][q][lane]+red[2][q][lane]+red[3][q][lane];
      atomicAdd(&accFrac[(q>>1)*128 + (q&1)*64 + lane], v);
    }
  }
}

// ---------------- finalize: mean-nei via (acc256/N)@W2^T (f32), frac chain, fc2
__global__ __launch_bounds__(256) void k_finalize(const float* __restrict__ acc256,
    const float* __restrict__ accFrac, const float* __restrict__ W2,
    const float* __restrict__ frw, const float* __restrict__ frf,
    const float* __restrict__ fc2, float* __restrict__ out, float invN)
{
  __shared__ float mh[256], nei[64], g[384], mm[192], hfrac[64];
  int t = threadIdx.x;
  mh[t] = acc256[t] * invN;
  for (int i = t; i < 384; i += 256) g[i] = accFrac[i] * invN;
  __syncthreads();
  if (t < 64){
    float s = 0.f;
    for (int k = 0; k < 256; k++) s += W2[t*256 + k] * mh[k];
    nei[t] = s;
  }
  for (int i = t; i < 192; i += 256){
    int s = i >> 6, d = i & 63;
    const float* w = frw + (size_t)(s*64 + d)*128;
    const float* gs = g + s*128;
    float sum = 0.f;
    for (int k = 0; k < 128; k++) sum += gs[k]*w[k];
    mm[i] = sum;
  }
  __syncthreads();
  if (t < 64){
    float s = 0.f;
    for (int k = 0; k < 192; k++) s += mm[k]*frf[t*192 + k];
    hfrac[t] = s;
  }
  __syncthreads();
  if (t < 64){
    float o = 0.f;
    for (int k = 0; k < 64; k++)
      o += fc2[t*128 + k]*nei[k] + fc2[t*128 + 64 + k]*hfrac[k];
    out[t] = o;
  }
}

extern "C" void kernel_launch(void* const* d_in, const int* in_sizes, int n_in,
                              void* d_out, int out_size, void* d_ws, size_t ws_size,
                              hipStream_t stream)
{
  const float* h    = (const float*)d_in[0];
  const int*   srcI = (const int*)  d_in[1];
  const int*   dstI = (const int*)  d_in[2];
  const int*   fcm  = (const int*)  d_in[3];
  const float* l1fc = (const float*)d_in[4];
  const float* l1at = (const float*)d_in[5];
  const float* l2fc = (const float*)d_in[6];
  const float* l2at = (const float*)d_in[7];
  const float* frw  = (const float*)d_in[8];
  const float* frf  = (const float*)d_in[9];
  const float* fc2  = (const float*)d_in[10];
  float* out = (float*)d_out;
  (void)n_in; (void)out_size; (void)ws_size;

  const int N = in_sizes[0] / 128;
  const int E = in_sizes[1];
  const int B = (N + 256) / 256;     // ceil((N+1)/256) so rowptr[N] is covered
  const int PAD = B * 256;

  char* w = (char*)d_ws;
  size_t off = 0;
  auto alloc = [&](size_t bytes) -> char* {
    char* p = w + off; off = (off + bytes + 255) & ~(size_t)255; return p;
  };
  uint2*  zb    = (uint2*) alloc((size_t)N*64*8);    // 51.2 MB packed bf16 z
  uint_t* hneib = (uint_t*)alloc((size_t)N*128*4);   // 51.2 MB packed bf16 hnei
  float* s1s  = (float*)alloc((size_t)N*4*4);
  float* s1d  = (float*)alloc((size_t)N*4*4);
  float* s2s  = (float*)alloc((size_t)N*4);
  float* s2d  = (float*)alloc((size_t)N*4);
  // ---- zeroed region (one memset): deg, den, wsrc, acc256, accFrac
  int*   deg     = (int*)  alloc((size_t)PAD*4);
  float* den     = (float*)alloc((size_t)N*4);
  float* wsrc    = (float*)alloc((size_t)N*4);
  float* acc256  = (float*)alloc(256*4);
  float* accFrac = (float*)alloc(384*4);
  const size_t zbytes = (size_t)((char*)accFrac + 384*4 - (char*)deg);
  // ---- rest
  int*   rowptr = (int*)alloc((size_t)PAD*4);
  int*   cursor = (int*)alloc((size_t)PAD*4);
  int*   part   = (int*)alloc(512*4);
  int*   csr    = (int*)alloc((size_t)E*4);
  ushort_t* w1bp = (ushort_t*)alloc(34816*2);   // 16 z-tiles + 1 score tile
  float* v2     = (float*)alloc(512*4);

  hipMemsetAsync(deg, 0, zbytes, stream);

  hipLaunchKernelGGL(k_wpack,   dim3(130),           dim3(256), 0, stream,
                     l1fc, l2fc, l1at, l2at, w1bp, v2);
  hipLaunchKernelGGL(k_hist,    dim3((E+255)/256),   dim3(256), 0, stream, dstI, deg, E);
  hipLaunchKernelGGL(k_scan1,   dim3(B),             dim3(256), 0, stream, deg, part);
  hipLaunchKernelGGL(k_scan2,   dim3(1),             dim3(512), 0, stream, part, B);
  hipLaunchKernelGGL(k_scan3,   dim3(B),             dim3(256), 0, stream, deg, part, rowptr, cursor);
  hipLaunchKernelGGL(k_scatter, dim3((E+255)/256),   dim3(256), 0, stream, srcI, dstI, cursor, csr, E);
  hipLaunchKernelGGL(k_gemm1m,  dim3((N+127)/128),   dim3(512), 0, stream,
                     h, w1bp, zb, s1s, s1d, N);
  hipLaunchKernelGGL(k_gat1,    dim3((N+3)/4),       dim3(256), 0, stream,
                     zb, s1s, s1d, rowptr, csr, v2, hneib, s2s, s2d, N);
  hipLaunchKernelGGL(k_denom2,  dim3((E+255)/256),   dim3(256), 0, stream,
                     srcI, dstI, s2s, s2d, den, E);
  hipLaunchKernelGGL(k_wsum,    dim3((E+255)/256),   dim3(256), 0, stream,
                     srcI, dstI, s2s, s2d, den, wsrc, E);
  hipLaunchKernelGGL(k_hsum,    dim3(2048),          dim3(256), 0, stream,
                     hneib, wsrc, acc256, N);
  hipLaunchKernelGGL(k_frac,    dim3(1024),          dim3(256), 0, stream, h, fcm, accFrac, N);
  hipLaunchKernelGGL(k_finalize,dim3(1),             dim3(256), 0, stream,
                     acc256, accFrac, l2fc, frw, frf, fc2, out, 1.0f/(float)N);
}

// Round 9
// 665.510 us; speedup vs baseline: 1.1398x; 1.1398x over previous
//
#include <hip/hip_runtime.h>
#include <math.h>

// GAT pipeline. Layer2 collapsed: mean(GAT2) = (Σ_s w_s hnei[s])@W2^T with
// w_s = Σ_{e:src=s} α_e. s2 scores fused in gat1 epilogue (v2 = W2^T a2).
// w_s computed by ONE CSR wave-per-dst kernel (LDS-cached exps, shfl denom,
// one atomic per edge) — R8's three-pass edge-atomic chain was the regression.

#define CAP 128   // per-wave LDS edge cache; deg>CAP falls back to recompute

typedef unsigned int  uint_t;
typedef unsigned short ushort_t;
typedef __attribute__((ext_vector_type(8))) short short8;
typedef __attribute__((ext_vector_type(4))) float floatx4;

__device__ __forceinline__ float wred_sum(float v){
#pragma unroll
  for (int o = 1; o < 64; o <<= 1) v += __shfl_xor(v, o, 64);
  return v;
}
__device__ __forceinline__ float lrelu(float x){ return x >= 0.f ? x : 0.01f*x; }
__device__ __forceinline__ ushort_t f2b(float f){
  uint_t u = __float_as_uint(f);
  u = (u + 0x7FFFu + ((u >> 16) & 1u)) >> 16;   // RNE
  return (ushort_t)u;
}
__device__ __forceinline__ float b2f_lo(uint_t w){ return __uint_as_float(w << 16); }
__device__ __forceinline__ float b2f_hi(uint_t w){ return __uint_as_float(w & 0xFFFF0000u); }

// ---------------- pack: W1 tiles (bx 0..127), layer1 score tile (bx 128),
// v2 = [W2^T a2_src ; W2^T a2_dst] f32 (bx 129)
__global__ void k_wpack(const float* __restrict__ W1, const float* __restrict__ W2,
                        const float* __restrict__ a1, const float* __restrict__ a2,
                        ushort_t* __restrict__ w1bp, float* __restrict__ v2){
  __shared__ float v[8][128];
  const int bx = blockIdx.x, t = threadIdx.x;
  if (bx < 128){
    int idx = bx*256 + t;
    int j = idx & 7, lane = (idx >> 3) & 63, ks = (idx >> 9) & 3, tt = idx >> 11;
    int n = tt*16 + (lane & 15), k = ks*32 + (lane >> 4)*8 + j;
    w1bp[idx] = f2b(W1[n*128 + k]);
  } else if (bx == 128){
    // layer1 score tile: col 0..3 = src score vec per head, 4..7 = dst
    for (int o = t; o < 1024; o += 256){
      int col = o >> 7, k = o & 127, hh = col & 3, off = (col >> 2)*64;
      float s = 0.f;
      for (int n = 0; n < 64; n++) s += a1[hh*128 + off + n] * W1[(hh*64 + n)*128 + k];
      v[col][k] = s;
    }
    __syncthreads();
    for (int idx = t; idx < 2048; idx += 256){
      int j = idx & 7, lane = (idx >> 3) & 63, ks = idx >> 9;
      int col = lane & 15, k = ks*32 + (lane >> 4)*8 + j;
      w1bp[32768 + idx] = (col < 8) ? f2b(v[col][k]) : (ushort_t)0;
    }
  } else {
    // v2[k] = sum_j W2[j][k]*a2[j]; v2[256+k] = sum_j W2[j][k]*a2[64+j]
    float s0 = 0.f, s1 = 0.f;
    for (int j = 0; j < 64; j++){
      float wjk = W2[j*256 + t];
      s0 += wjk * a2[j];
      s1 += wjk * a2[64 + j];
    }
    v2[t] = s0; v2[256 + t] = s1;
  }
}

// ---------------- GEMM1 (MFMA, split-A, LDS-staged B): zb + layer1 scores
__global__ __launch_bounds__(512) void k_gemm1m(const float* __restrict__ h,
    const ushort_t* __restrict__ w1bp,
    uint2* __restrict__ zb, float* __restrict__ s1s, float* __restrict__ s1d, int N)
{
  __shared__ __align__(16) ushort_t ldsB[34816];   // 69,632 B
  const int tid = threadIdx.x;
  {
    const uint4* src = (const uint4*)w1bp;
    uint4* dst = (uint4*)ldsB;
    for (int i = tid; i < 4352; i += 512) dst[i] = src[i];
  }
  __syncthreads();
  const int wave = tid >> 6, lane = tid & 63;
  const int quad = lane >> 4, l16 = lane & 15;
  const int row0 = blockIdx.x*128 + wave*16;
  if (row0 >= N) return;
  const int ar = (row0 + l16 < N) ? (row0 + l16) : (N - 1);   // clamp; dups discarded
  floatx4 c[17];
#pragma unroll
  for (int t = 0; t < 17; t++) c[t] = (floatx4){0.f,0.f,0.f,0.f};
#pragma unroll
  for (int ks = 0; ks < 4; ks++){
    const float* ap = &h[(size_t)ar*128 + ks*32 + quad*8];
    float4 v0 = *(const float4*)ap;
    float4 v1 = *(const float4*)(ap + 4);
    float vv[8] = {v0.x,v0.y,v0.z,v0.w,v1.x,v1.y,v1.z,v1.w};
    short8 ahi, alo;
#pragma unroll
    for (int j = 0; j < 8; j++){
      ushort_t hb = f2b(vv[j]);
      float hf = __uint_as_float((uint_t)hb << 16);
      ahi[j] = (short)hb;
      alo[j] = (short)f2b(vv[j] - hf);
    }
#pragma unroll
    for (int t = 0; t < 17; t++){
      short8 b = *(const short8*)&ldsB[(size_t)((t*4 + ks)*64 + lane)*8];
      c[t] = __builtin_amdgcn_mfma_f32_16x16x32_bf16(ahi, b, c[t], 0, 0, 0);
      c[t] = __builtin_amdgcn_mfma_f32_16x16x32_bf16(alo, b, c[t], 0, 0, 0);
    }
  }
#pragma unroll
  for (int i = 0; i < 4; i++){
    const int r = row0 + quad*4 + i;
    if (r >= N) continue;
#pragma unroll
    for (int m = 0; m < 4; m++){
      uint_t w0 = (uint_t)f2b(c[0*4+m][i]) | ((uint_t)f2b(c[1*4+m][i]) << 16);
      uint_t w1 = (uint_t)f2b(c[2*4+m][i]) | ((uint_t)f2b(c[3*4+m][i]) << 16);
      zb[(size_t)r*64 + m*16 + l16] = make_uint2(w0, w1);
    }
    const float sv = c[16][i];
    if (l16 < 4) s1s[r*4 + l16] = sv;
    else if (l16 < 8) s1d[r*4 + (l16 - 4)] = sv;
  }
}

// ---------------- CSR build
__global__ void k_hist(const int* __restrict__ d, int* __restrict__ deg, int E){
  int i = blockIdx.x*256 + threadIdx.x;
  if (i < E) atomicAdd(&deg[d[i]], 1);
}
__global__ __launch_bounds__(256) void k_scan1(const int* __restrict__ deg, int* __restrict__ part){
  __shared__ int tmp[256];
  int t = threadIdx.x;
  tmp[t] = deg[blockIdx.x*256 + t];
  __syncthreads();
  for (int off = 128; off > 0; off >>= 1){
    if (t < off) tmp[t] += tmp[t+off];
    __syncthreads();
  }
  if (t == 0) part[blockIdx.x] = tmp[0];
}
__global__ __launch_bounds__(512) void k_scan2(int* __restrict__ part, int B){
  __shared__ int tmp[512];
  int t = threadIdx.x;
  int v = (t < B) ? part[t] : 0;
  tmp[t] = v; __syncthreads();
  for (int off = 1; off < 512; off <<= 1){
    int x = (t >= off) ? tmp[t-off] : 0;
    __syncthreads();
    tmp[t] += x;
    __syncthreads();
  }
  if (t < B) part[t] = tmp[t] - v;   // exclusive
}
__global__ __launch_bounds__(256) void k_scan3(const int* __restrict__ deg, const int* __restrict__ part,
    int* __restrict__ rowptr, int* __restrict__ cursor){
  __shared__ int tmp[256];
  int t = threadIdx.x, i = blockIdx.x*256 + t;
  int v = deg[i];
  tmp[t] = v; __syncthreads();
  for (int off = 1; off < 256; off <<= 1){
    int x = (t >= off) ? tmp[t-off] : 0;
    __syncthreads();
    tmp[t] += x;
    __syncthreads();
  }
  int excl = tmp[t] - v + part[blockIdx.x];
  rowptr[i] = excl; cursor[i] = excl;
}
__global__ void k_scatter(const int* __restrict__ s, const int* __restrict__ d,
    int* __restrict__ cursor, int* __restrict__ csr, int E){
  int i = blockIdx.x*256 + threadIdx.x;
  if (i < E){
    int p = atomicAdd(&cursor[d[i]], 1);
    csr[p] = s[i];
  }
}

// ---------------- layer1 GAT aggregation + ELU -> hneib bf16 + fused layer2 scores
__global__ __launch_bounds__(256) void k_gat1(
    const uint2* __restrict__ zb, const float* __restrict__ s1src, const float* __restrict__ s1dst,
    const int* __restrict__ rowptr, const int* __restrict__ csr, const float* __restrict__ v2,
    uint_t* __restrict__ hneib, float* __restrict__ s2s, float* __restrict__ s2d, int N)
{
  __shared__ int   sbuf[4][CAP];
  __shared__ __align__(16) float4 ebuf[4][CAP];
  __shared__ float v2s[512];
  const int tid = threadIdx.x;
  v2s[tid] = v2[tid];
  v2s[tid + 256] = v2[tid + 256];
  __syncthreads();
  const int wave = tid >> 6, lane = tid & 63;
  const int dst = blockIdx.x*4 + wave;
  if (dst >= N) return;
  const int beg = rowptr[dst];
  const int deg = rowptr[dst+1] - beg;
  const float4 sd = *(const float4*)&s1dst[dst*4];
  float t0=0.f,t1=0.f,t2=0.f,t3=0.f;
  for (int j = lane; j < deg; j += 64){
    int s = csr[beg+j];
    float4 sv = *(const float4*)&s1src[s*4];
    float4 a;
    a.x = __expf(lrelu(sv.x+sd.x)); a.y = __expf(lrelu(sv.y+sd.y));
    a.z = __expf(lrelu(sv.z+sd.z)); a.w = __expf(lrelu(sv.w+sd.w));
    if (j < CAP){ sbuf[wave][j] = s; ebuf[wave][j] = a; }
    t0 += a.x; t1 += a.y; t2 += a.z; t3 += a.w;
  }
  const float inv[4] = {1.f/wred_sum(t0), 1.f/wred_sum(t1), 1.f/wred_sum(t2), 1.f/wred_sum(t3)};
  const int eh = lane >> 5, li = lane & 31;
  float acc[2][4] = {};
  int jj = 0;
  if (deg <= CAP){
    for (; jj + 2 <= deg; jj += 2){
      const int j = jj + eh;
      int s = sbuf[wave][j]; float4 al = ebuf[wave][j];
      uint4 u = *((const uint4*)(zb + (size_t)s*64) + li);
      acc[0][0] += al.x * b2f_lo(u.x);
      acc[0][1] += al.y * b2f_hi(u.x);
      acc[0][2] += al.z * b2f_lo(u.y);
      acc[0][3] += al.w * b2f_hi(u.y);
      acc[1][0] += al.x * b2f_lo(u.z);
      acc[1][1] += al.y * b2f_hi(u.z);
      acc[1][2] += al.z * b2f_lo(u.w);
      acc[1][3] += al.w * b2f_hi(u.w);
    }
    if (jj < deg && eh == 0){
      int s = sbuf[wave][jj]; float4 al = ebuf[wave][jj];
      uint4 u = *((const uint4*)(zb + (size_t)s*64) + li);
      acc[0][0] += al.x * b2f_lo(u.x);
      acc[0][1] += al.y * b2f_hi(u.x);
      acc[0][2] += al.z * b2f_lo(u.y);
      acc[0][3] += al.w * b2f_hi(u.y);
      acc[1][0] += al.x * b2f_lo(u.z);
      acc[1][1] += al.y * b2f_hi(u.z);
      acc[1][2] += al.z * b2f_lo(u.w);
      acc[1][3] += al.w * b2f_hi(u.w);
    }
  } else {
    for (; jj < deg; jj += 2){
      const int j = jj + eh;
      const bool v = j < deg;
      const int jc = v ? j : jj;
      int s; float4 al;
      if (jc < CAP){ s = sbuf[wave][jc]; al = ebuf[wave][jc]; }
      else {
        s = csr[beg+jc];
        float4 sv = *(const float4*)&s1src[s*4];
        al.x = __expf(lrelu(sv.x+sd.x)); al.y = __expf(lrelu(sv.y+sd.y));
        al.z = __expf(lrelu(sv.z+sd.z)); al.w = __expf(lrelu(sv.w+sd.w));
      }
      if (!v){ al.x=0.f; al.y=0.f; al.z=0.f; al.w=0.f; }
      uint4 u = *((const uint4*)(zb + (size_t)s*64) + li);
      acc[0][0] += al.x * b2f_lo(u.x);
      acc[0][1] += al.y * b2f_hi(u.x);
      acc[0][2] += al.z * b2f_lo(u.y);
      acc[0][3] += al.w * b2f_hi(u.y);
      acc[1][0] += al.x * b2f_lo(u.z);
      acc[1][1] += al.y * b2f_hi(u.z);
      acc[1][2] += al.z * b2f_lo(u.w);
      acc[1][3] += al.w * b2f_hi(u.w);
    }
  }
#pragma unroll
  for (int k = 0; k < 2; k++)
#pragma unroll
    for (int hh = 0; hh < 4; hh++) acc[k][hh] += __shfl_xor(acc[k][hh], 32, 64);
  // ELU + fused s2 score dot (half0 = src vec, half1 = dst vec)
  const float* vv = &v2s[eh*256];
  float p = 0.f;
#pragma unroll
  for (int hh = 0; hh < 4; hh++){
    float e0 = acc[0][hh]*inv[hh]; e0 = e0 > 0.f ? e0 : expm1f(e0);
    float e1 = acc[1][hh]*inv[hh]; e1 = e1 > 0.f ? e1 : expm1f(e1);
    p += e0 * vv[hh*64 + 2*li] + e1 * vv[hh*64 + 2*li + 1];
    if (eh == 0)
      hneib[(size_t)dst*128 + hh*32 + li] = (uint_t)f2b(e0) | ((uint_t)f2b(e1) << 16);
  }
#pragma unroll
  for (int o = 1; o < 32; o <<= 1) p += __shfl_xor(p, o, 64);
  if (lane == 0)  s2s[dst] = p;
  if (lane == 32) s2d[dst] = p;
}

// ---------------- layer2 alpha-weights: wave per dst over CSR; one atomic per edge
__global__ __launch_bounds__(256) void k_aw2(
    const float* __restrict__ s2s, const float* __restrict__ s2d,
    const int* __restrict__ rowptr, const int* __restrict__ csr,
    float* __restrict__ wsrc, int N)
{
  __shared__ int   sbuf[4][CAP];
  __shared__ float ebuf[4][CAP];
  const int wave = threadIdx.x >> 6, lane = threadIdx.x & 63;
  const int dst = blockIdx.x*4 + wave;
  if (dst >= N) return;
  const int beg = rowptr[dst], deg = rowptr[dst+1] - beg;
  const float sd = s2d[dst];
  float ts = 0.f;
  for (int j = lane; j < deg; j += 64){
    int s = csr[beg+j];
    float a = __expf(lrelu(s2s[s] + sd));
    if (j < CAP){ sbuf[wave][j] = s; ebuf[wave][j] = a; }
    ts += a;
  }
  const float inv = 1.f/wred_sum(ts);
  for (int j = lane; j < deg; j += 64){
    int s; float a;
    if (j < CAP){ s = sbuf[wave][j]; a = ebuf[wave][j]; }
    else { s = csr[beg+j]; a = __expf(lrelu(s2s[s] + sd)); }
    atomicAdd(&wsrc[s], a * inv);
  }
}

// ---------------- weighted hnei sum (coalesced): acc256[dim] = sum_n w[n]*hnei[n][dim]
__global__ __launch_bounds__(256) void k_hsum(const uint_t* __restrict__ hneib,
    const float* __restrict__ wsrc, float* __restrict__ acc256, int N)
{
  __shared__ float pr[512];
  const int t = threadIdx.x;
  const int h2 = t >> 7, p = t & 127;
  float a0 = 0.f, a1 = 0.f;
  const int step = gridDim.x * 2;
  for (int n = blockIdx.x*2 + h2; n < N; n += step){
    float wn = wsrc[n];
    uint_t u = hneib[(size_t)n*128 + p];
    a0 += wn * b2f_lo(u);
    a1 += wn * b2f_hi(u);
  }
  pr[h2*256 + 2*p]     = a0;
  pr[h2*256 + 2*p + 1] = a1;
  __syncthreads();
  float v = pr[t] + pr[256 + t];
  int pp = t >> 1;
  int d = (pp >> 5)*64 + 2*(pp & 31) + (t & 1);
  atomicAdd(&acc256[d], v);
}

// ---------------- fractal: accFrac[s*128+k] = sum_n h[fcm[n,s]][k]   (exact f32)
__global__ __launch_bounds__(256) void k_frac(const float* __restrict__ h,
    const int* __restrict__ fcm, float* __restrict__ accFrac, int N)
{
  __shared__ float red[4][6][64];
  const int wave = threadIdx.x >> 6, lane = threadIdx.x & 63;
  float a[6] = {0.f,0.f,0.f,0.f,0.f,0.f};
  const int stride = gridDim.x * 4;
  for (int n = blockIdx.x*4 + wave; n < N; n += stride){
    int i0 = fcm[n*3], i1 = fcm[n*3+1], i2 = fcm[n*3+2];
    a[0] += h[(size_t)i0*128 + lane]; a[1] += h[(size_t)i0*128 + 64 + lane];
    a[2] += h[(size_t)i1*128 + lane]; a[3] += h[(size_t)i1*128 + 64 + lane];
    a[4] += h[(size_t)i2*128 + lane]; a[5] += h[(size_t)i2*128 + 64 + lane];
  }
#pragma unroll
  for (int q = 0; q < 6; q++) red[wave][q][lane] = a[q];
  __syncthreads();
  if (wave == 0){
#pragma unroll
    for (int q = 0; q < 6; q++){
      float v = red[0][q][lane]+red[1][q][lane]+red[2][q][lane]+red[3][q][lane];
      atomicAdd(&accFrac[(q>>1)*128 + (q&1)*64 + lane], v);
    }
  }
}

// ---------------- finalize: mean-nei via (acc256/N)@W2^T (f32), frac chain, fc2
__global__ __launch_bounds__(256) void k_finalize(const float* __restrict__ acc256,
    const float* __restrict__ accFrac, const float* __restrict__ W2,
    const float* __restrict__ frw, const float* __restrict__ frf,
    const float* __restrict__ fc2, float* __restrict__ out, float invN)
{
  __shared__ float mh[256], nei[64], g[384], mm[192], hfrac[64];
  int t = threadIdx.x;
  mh[t] = acc256[t] * invN;
  for (int i = t; i < 384; i += 256) g[i] = accFrac[i] * invN;
  __syncthreads();
  if (t < 64){
    float s = 0.f;
    for (int k = 0; k < 256; k++) s += W2[t*256 + k] * mh[k];
    nei[t] = s;
  }
  for (int i = t; i < 192; i += 256){
    int s = i >> 6, d = i & 63;
    const float* w = frw + (size_t)(s*64 + d)*128;
    const float* gs = g + s*128;
    float sum = 0.f;
    for (int k = 0; k < 128; k++) sum += gs[k]*w[k];
    mm[i] = sum;
  }
  __syncthreads();
  if (t < 64){
    float s = 0.f;
    for (int k = 0; k < 192; k++) s += mm[k]*frf[t*192 + k];
    hfrac[t] = s;
  }
  __syncthreads();
  if (t < 64){
    float o = 0.f;
    for (int k = 0; k < 64; k++)
      o += fc2[t*128 + k]*nei[k] + fc2[t*128 + 64 + k]*hfrac[k];
    out[t] = o;
  }
}

extern "C" void kernel_launch(void* const* d_in, const int* in_sizes, int n_in,
                              void* d_out, int out_size, void* d_ws, size_t ws_size,
                              hipStream_t stream)
{
  const float* h    = (const float*)d_in[0];
  const int*   srcI = (const int*)  d_in[1];
  const int*   dstI = (const int*)  d_in[2];
  const int*   fcm  = (const int*)  d_in[3];
  const float* l1fc = (const float*)d_in[4];
  const float* l1at = (const float*)d_in[5];
  const float* l2fc = (const float*)d_in[6];
  const float* l2at = (const float*)d_in[7];
  const float* frw  = (const float*)d_in[8];
  const float* frf  = (const float*)d_in[9];
  const float* fc2  = (const float*)d_in[10];
  float* out = (float*)d_out;
  (void)n_in; (void)out_size; (void)ws_size;

  const int N = in_sizes[0] / 128;
  const int E = in_sizes[1];
  const int B = (N + 256) / 256;     // ceil((N+1)/256) so rowptr[N] is covered
  const int PAD = B * 256;

  char* w = (char*)d_ws;
  size_t off = 0;
  auto alloc = [&](size_t bytes) -> char* {
    char* p = w + off; off = (off + bytes + 255) & ~(size_t)255; return p;
  };
  uint2*  zb    = (uint2*) alloc((size_t)N*64*8);    // 51.2 MB packed bf16 z
  uint_t* hneib = (uint_t*)alloc((size_t)N*128*4);   // 51.2 MB packed bf16 hnei
  float* s1s  = (float*)alloc((size_t)N*4*4);
  float* s1d  = (float*)alloc((size_t)N*4*4);
  float* s2s  = (float*)alloc((size_t)N*4);
  float* s2d  = (float*)alloc((size_t)N*4);
  // ---- zeroed region (one memset): deg, wsrc, acc256, accFrac
  int*   deg     = (int*)  alloc((size_t)PAD*4);
  float* wsrc    = (float*)alloc((size_t)N*4);
  float* acc256  = (float*)alloc(256*4);
  float* accFrac = (float*)alloc(384*4);
  const size_t zbytes = (size_t)((char*)accFrac + 384*4 - (char*)deg);
  // ---- rest
  int*   rowptr = (int*)alloc((size_t)PAD*4);
  int*   cursor = (int*)alloc((size_t)PAD*4);
  int*   part   = (int*)alloc(512*4);
  int*   csr    = (int*)alloc((size_t)E*4);
  ushort_t* w1bp = (ushort_t*)alloc(34816*2);   // 16 z-tiles + 1 score tile
  float* v2     = (float*)alloc(512*4);

  hipMemsetAsync(deg, 0, zbytes, stream);

  hipLaunchKernelGGL(k_wpack,   dim3(130),           dim3(256), 0, stream,
                     l1fc, l2fc, l1at, l2at, w1bp, v2);
  hipLaunchKernelGGL(k_hist,    dim3((E+255)/256),   dim3(256), 0, stream, dstI, deg, E);
  hipLaunchKernelGGL(k_scan1,   dim3(B),             dim3(256), 0, stream, deg, part);
  hipLaunchKernelGGL(k_scan2,   dim3(1),             dim3(512), 0, stream, part, B);
  hipLaunchKernelGGL(k_scan3,   dim3(B),             dim3(256), 0, stream, deg, part, rowptr, cursor);
  hipLaunchKernelGGL(k_scatter, dim3((E+255)/256),   dim3(256), 0, stream, srcI, dstI, cursor, csr, E);
  hipLaunchKernelGGL(k_gemm1m,  dim3((N+127)/128),   dim3(512), 0, stream,
                     h, w1bp, zb, s1s, s1d, N);
  hipLaunchKernelGGL(k_gat1,    dim3((N+3)/4),       dim3(256), 0, stream,
                     zb, s1s, s1d, rowptr, csr, v2, hneib, s2s, s2d, N);
  hipLaunchKernelGGL(k_aw2,     dim3((N+3)/4),       dim3(256), 0, stream,
                     s2s, s2d, rowptr, csr, wsrc, N);
  hipLaunchKernelGGL(k_hsum,    dim3(608),           dim3(256), 0, stream,
                     hneib, wsrc, acc256, N);
  hipLaunchKernelGGL(k_frac,    dim3(1024),          dim3(256), 0, stream, h, fcm, accFrac, N);
  hipLaunchKernelGGL(k_finalize,dim3(1),             dim3(256), 0, stream,
                     acc256, accFrac, l2fc, frw, frf, fc2, out, 1.0f/(float)N);
}

// Round 10
// 660.788 us; speedup vs baseline: 1.1479x; 1.0071x over previous
//
#include <hip/hip_runtime.h>
#include <math.h>

// GAT pipeline. Layer2 collapsed: mean(GAT2) = (Σ_s w_s hnei[s])@W2^T with
// w_s = Σ_{e:src=s} α_e (CSR wave-per-dst). s2 scores fused in gat1 (v2=W2^T a2).
// GEMM1: MFMA, LDS-staged B; split-A lo-correction ONLY on the score tile
// (z output is bf16-rounded anyway). frac: float4 whole-row loads.

#define CAP 128   // per-wave LDS edge cache; deg>CAP falls back to recompute

typedef unsigned int  uint_t;
typedef unsigned short ushort_t;
typedef __attribute__((ext_vector_type(8))) short short8;
typedef __attribute__((ext_vector_type(4))) float floatx4;

__device__ __forceinline__ float wred_sum(float v){
#pragma unroll
  for (int o = 1; o < 64; o <<= 1) v += __shfl_xor(v, o, 64);
  return v;
}
__device__ __forceinline__ float lrelu(float x){ return x >= 0.f ? x : 0.01f*x; }
__device__ __forceinline__ ushort_t f2b(float f){
  uint_t u = __float_as_uint(f);
  u = (u + 0x7FFFu + ((u >> 16) & 1u)) >> 16;   // RNE
  return (ushort_t)u;
}
__device__ __forceinline__ float b2f_lo(uint_t w){ return __uint_as_float(w << 16); }
__device__ __forceinline__ float b2f_hi(uint_t w){ return __uint_as_float(w & 0xFFFF0000u); }

// ---------------- pack: W1 tiles (bx 0..127), layer1 score tile (bx 128),
// v2 = [W2^T a2_src ; W2^T a2_dst] f32 (bx 129)
__global__ void k_wpack(const float* __restrict__ W1, const float* __restrict__ W2,
                        const float* __restrict__ a1, const float* __restrict__ a2,
                        ushort_t* __restrict__ w1bp, float* __restrict__ v2){
  __shared__ float v[8][128];
  const int bx = blockIdx.x, t = threadIdx.x;
  if (bx < 128){
    int idx = bx*256 + t;
    int j = idx & 7, lane = (idx >> 3) & 63, ks = (idx >> 9) & 3, tt = idx >> 11;
    int n = tt*16 + (lane & 15), k = ks*32 + (lane >> 4)*8 + j;
    w1bp[idx] = f2b(W1[n*128 + k]);
  } else if (bx == 128){
    // layer1 score tile: col 0..3 = src score vec per head, 4..7 = dst
    for (int o = t; o < 1024; o += 256){
      int col = o >> 7, k = o & 127, hh = col & 3, off = (col >> 2)*64;
      float s = 0.f;
      for (int n = 0; n < 64; n++) s += a1[hh*128 + off + n] * W1[(hh*64 + n)*128 + k];
      v[col][k] = s;
    }
    __syncthreads();
    for (int idx = t; idx < 2048; idx += 256){
      int j = idx & 7, lane = (idx >> 3) & 63, ks = idx >> 9;
      int col = lane & 15, k = ks*32 + (lane >> 4)*8 + j;
      w1bp[32768 + idx] = (col < 8) ? f2b(v[col][k]) : (ushort_t)0;
    }
  } else {
    // v2[k] = sum_j W2[j][k]*a2[j]; v2[256+k] = sum_j W2[j][k]*a2[64+j]
    float s0 = 0.f, s1 = 0.f;
    for (int j = 0; j < 64; j++){
      float wjk = W2[j*256 + t];
      s0 += wjk * a2[j];
      s1 += wjk * a2[64 + j];
    }
    v2[t] = s0; v2[256 + t] = s1;
  }
}

// ---------------- GEMM1 (MFMA, LDS-staged B): zb + layer1 scores
// z-tiles: single bf16 A (output bf16-rounded anyway); score tile: split hi+lo A.
__global__ __launch_bounds__(512) void k_gemm1m(const float* __restrict__ h,
    const ushort_t* __restrict__ w1bp,
    uint2* __restrict__ zb, float* __restrict__ s1s, float* __restrict__ s1d, int N)
{
  __shared__ __align__(16) ushort_t ldsB[34816];   // 69,632 B
  const int tid = threadIdx.x;
  {
    const uint4* src = (const uint4*)w1bp;
    uint4* dst = (uint4*)ldsB;
    for (int i = tid; i < 4352; i += 512) dst[i] = src[i];
  }
  __syncthreads();
  const int wave = tid >> 6, lane = tid & 63;
  const int quad = lane >> 4, l16 = lane & 15;
  const int row0 = blockIdx.x*128 + wave*16;
  if (row0 >= N) return;
  const int ar = (row0 + l16 < N) ? (row0 + l16) : (N - 1);   // clamp; dups discarded
  floatx4 c[17];
#pragma unroll
  for (int t = 0; t < 17; t++) c[t] = (floatx4){0.f,0.f,0.f,0.f};
#pragma unroll
  for (int ks = 0; ks < 4; ks++){
    const float* ap = &h[(size_t)ar*128 + ks*32 + quad*8];
    float4 v0 = *(const float4*)ap;
    float4 v1 = *(const float4*)(ap + 4);
    float vv[8] = {v0.x,v0.y,v0.z,v0.w,v1.x,v1.y,v1.z,v1.w};
    short8 ahi, alo;
#pragma unroll
    for (int j = 0; j < 8; j++){
      ushort_t hb = f2b(vv[j]);
      float hf = __uint_as_float((uint_t)hb << 16);
      ahi[j] = (short)hb;
      alo[j] = (short)f2b(vv[j] - hf);
    }
#pragma unroll
    for (int t = 0; t < 17; t++){
      short8 b = *(const short8*)&ldsB[(size_t)((t*4 + ks)*64 + lane)*8];
      c[t] = __builtin_amdgcn_mfma_f32_16x16x32_bf16(ahi, b, c[t], 0, 0, 0);
    }
    // lo-correction only for the score tile (t=16)
    {
      short8 b = *(const short8*)&ldsB[(size_t)((16*4 + ks)*64 + lane)*8];
      c[16] = __builtin_amdgcn_mfma_f32_16x16x32_bf16(alo, b, c[16], 0, 0, 0);
    }
  }
#pragma unroll
  for (int i = 0; i < 4; i++){
    const int r = row0 + quad*4 + i;
    if (r >= N) continue;
#pragma unroll
    for (int m = 0; m < 4; m++){
      uint_t w0 = (uint_t)f2b(c[0*4+m][i]) | ((uint_t)f2b(c[1*4+m][i]) << 16);
      uint_t w1 = (uint_t)f2b(c[2*4+m][i]) | ((uint_t)f2b(c[3*4+m][i]) << 16);
      zb[(size_t)r*64 + m*16 + l16] = make_uint2(w0, w1);
    }
    const float sv = c[16][i];
    if (l16 < 4) s1s[r*4 + l16] = sv;
    else if (l16 < 8) s1d[r*4 + (l16 - 4)] = sv;
  }
}

// ---------------- CSR build
__global__ void k_hist(const int* __restrict__ d, int* __restrict__ deg, int E){
  int i = blockIdx.x*256 + threadIdx.x;
  if (i < E) atomicAdd(&deg[d[i]], 1);
}
__global__ __launch_bounds__(256) void k_scan1(const int* __restrict__ deg, int* __restrict__ part){
  __shared__ int tmp[256];
  int t = threadIdx.x;
  tmp[t] = deg[blockIdx.x*256 + t];
  __syncthreads();
  for (int off = 128; off > 0; off >>= 1){
    if (t < off) tmp[t] += tmp[t+off];
    __syncthreads();
  }
  if (t == 0) part[blockIdx.x] = tmp[0];
}
__global__ __launch_bounds__(512) void k_scan2(int* __restrict__ part, int B){
  __shared__ int tmp[512];
  int t = threadIdx.x;
  int v = (t < B) ? part[t] : 0;
  tmp[t] = v; __syncthreads();
  for (int off = 1; off < 512; off <<= 1){
    int x = (t >= off) ? tmp[t-off] : 0;
    __syncthreads();
    tmp[t] += x;
    __syncthreads();
  }
  if (t < B) part[t] = tmp[t] - v;   // exclusive
}
__global__ __launch_bounds__(256) void k_scan3(const int* __restrict__ deg, const int* __restrict__ part,
    int* __restrict__ rowptr, int* __restrict__ cursor){
  __shared__ int tmp[256];
  int t = threadIdx.x, i = blockIdx.x*256 + t;
  int v = deg[i];
  tmp[t] = v; __syncthreads();
  for (int off = 1; off < 256; off <<= 1){
    int x = (t >= off) ? tmp[t-off] : 0;
    __syncthreads();
    tmp[t] += x;
    __syncthreads();
  }
  int excl = tmp[t] - v + part[blockIdx.x];
  rowptr[i] = excl; cursor[i] = excl;
}
__global__ void k_scatter(const int* __restrict__ s, const int* __restrict__ d,
    int* __restrict__ cursor, int* __restrict__ csr, int E){
  int i = blockIdx.x*256 + threadIdx.x;
  if (i < E){
    int p = atomicAdd(&cursor[d[i]], 1);
    csr[p] = s[i];
  }
}

// ---------------- layer1 GAT aggregation + ELU -> hneib bf16 + fused layer2 scores
__global__ __launch_bounds__(256) void k_gat1(
    const uint2* __restrict__ zb, const float* __restrict__ s1src, const float* __restrict__ s1dst,
    const int* __restrict__ rowptr, const int* __restrict__ csr, const float* __restrict__ v2,
    uint_t* __restrict__ hneib, float* __restrict__ s2s, float* __restrict__ s2d, int N)
{
  __shared__ int   sbuf[4][CAP];
  __shared__ __align__(16) float4 ebuf[4][CAP];
  __shared__ float v2s[512];
  const int tid = threadIdx.x;
  v2s[tid] = v2[tid];
  v2s[tid + 256] = v2[tid + 256];
  __syncthreads();
  const int wave = tid >> 6, lane = tid & 63;
  const int dst = blockIdx.x*4 + wave;
  if (dst >= N) return;
  const int beg = rowptr[dst];
  const int deg = rowptr[dst+1] - beg;
  const float4 sd = *(const float4*)&s1dst[dst*4];
  float t0=0.f,t1=0.f,t2=0.f,t3=0.f;
  for (int j = lane; j < deg; j += 64){
    int s = csr[beg+j];
    float4 sv = *(const float4*)&s1src[s*4];
    float4 a;
    a.x = __expf(lrelu(sv.x+sd.x)); a.y = __expf(lrelu(sv.y+sd.y));
    a.z = __expf(lrelu(sv.z+sd.z)); a.w = __expf(lrelu(sv.w+sd.w));
    if (j < CAP){ sbuf[wave][j] = s; ebuf[wave][j] = a; }
    t0 += a.x; t1 += a.y; t2 += a.z; t3 += a.w;
  }
  const float inv[4] = {1.f/wred_sum(t0), 1.f/wred_sum(t1), 1.f/wred_sum(t2), 1.f/wred_sum(t3)};
  const int eh = lane >> 5, li = lane & 31;
  float acc[2][4] = {};
  int jj = 0;
  if (deg <= CAP){
    for (; jj + 2 <= deg; jj += 2){
      const int j = jj + eh;
      int s = sbuf[wave][j]; float4 al = ebuf[wave][j];
      uint4 u = *((const uint4*)(zb + (size_t)s*64) + li);
      acc[0][0] += al.x * b2f_lo(u.x);
      acc[0][1] += al.y * b2f_hi(u.x);
      acc[0][2] += al.z * b2f_lo(u.y);
      acc[0][3] += al.w * b2f_hi(u.y);
      acc[1][0] += al.x * b2f_lo(u.z);
      acc[1][1] += al.y * b2f_hi(u.z);
      acc[1][2] += al.z * b2f_lo(u.w);
      acc[1][3] += al.w * b2f_hi(u.w);
    }
    if (jj < deg && eh == 0){
      int s = sbuf[wave][jj]; float4 al = ebuf[wave][jj];
      uint4 u = *((const uint4*)(zb + (size_t)s*64) + li);
      acc[0][0] += al.x * b2f_lo(u.x);
      acc[0][1] += al.y * b2f_hi(u.x);
      acc[0][2] += al.z * b2f_lo(u.y);
      acc[0][3] += al.w * b2f_hi(u.y);
      acc[1][0] += al.x * b2f_lo(u.z);
      acc[1][1] += al.y * b2f_hi(u.z);
      acc[1][2] += al.z * b2f_lo(u.w);
      acc[1][3] += al.w * b2f_hi(u.w);
    }
  } else {
    for (; jj < deg; jj += 2){
      const int j = jj + eh;
      const bool v = j < deg;
      const int jc = v ? j : jj;
      int s; float4 al;
      if (jc < CAP){ s = sbuf[wave][jc]; al = ebuf[wave][jc]; }
      else {
        s = csr[beg+jc];
        float4 sv = *(const float4*)&s1src[s*4];
        al.x = __expf(lrelu(sv.x+sd.x)); al.y = __expf(lrelu(sv.y+sd.y));
        al.z = __expf(lrelu(sv.z+sd.z)); al.w = __expf(lrelu(sv.w+sd.w));
      }
      if (!v){ al.x=0.f; al.y=0.f; al.z=0.f; al.w=0.f; }
      uint4 u = *((const uint4*)(zb + (size_t)s*64) + li);
      acc[0][0] += al.x * b2f_lo(u.x);
      acc[0][1] += al.y * b2f_hi(u.x);
      acc[0][2] += al.z * b2f_lo(u.y);
      acc[0][3] += al.w * b2f_hi(u.y);
      acc[1][0] += al.x * b2f_lo(u.z);
      acc[1][1] += al.y * b2f_hi(u.z);
      acc[1][2] += al.z * b2f_lo(u.w);
      acc[1][3] += al.w * b2f_hi(u.w);
    }
  }
#pragma unroll
  for (int k = 0; k < 2; k++)
#pragma unroll
    for (int hh = 0; hh < 4; hh++) acc[k][hh] += __shfl_xor(acc[k][hh], 32, 64);
  // ELU + fused s2 score dot (half0 = src vec, half1 = dst vec)
  const float* vv = &v2s[eh*256];
  float p = 0.f;
#pragma unroll
  for (int hh = 0; hh < 4; hh++){
    float e0 = acc[0][hh]*inv[hh]; e0 = e0 > 0.f ? e0 : expm1f(e0);
    float e1 = acc[1][hh]*inv[hh]; e1 = e1 > 0.f ? e1 : expm1f(e1);
    p += e0 * vv[hh*64 + 2*li] + e1 * vv[hh*64 + 2*li + 1];
    if (eh == 0)
      hneib[(size_t)dst*128 + hh*32 + li] = (uint_t)f2b(e0) | ((uint_t)f2b(e1) << 16);
  }
#pragma unroll
  for (int o = 1; o < 32; o <<= 1) p += __shfl_xor(p, o, 64);
  if (lane == 0)  s2s[dst] = p;
  if (lane == 32) s2d[dst] = p;
}

// ---------------- layer2 alpha-weights: wave per dst over CSR; one atomic per edge
__global__ __launch_bounds__(256) void k_aw2(
    const float* __restrict__ s2s, const float* __restrict__ s2d,
    const int* __restrict__ rowptr, const int* __restrict__ csr,
    float* __restrict__ wsrc, int N)
{
  __shared__ int   sbuf[4][CAP];
  __shared__ float ebuf[4][CAP];
  const int wave = threadIdx.x >> 6, lane = threadIdx.x & 63;
  const int dst = blockIdx.x*4 + wave;
  if (dst >= N) return;
  const int beg = rowptr[dst], deg = rowptr[dst+1] - beg;
  const float sd = s2d[dst];
  float ts = 0.f;
  for (int j = lane; j < deg; j += 64){
    int s = csr[beg+j];
    float a = __expf(lrelu(s2s[s] + sd));
    if (j < CAP){ sbuf[wave][j] = s; ebuf[wave][j] = a; }
    ts += a;
  }
  const float inv = 1.f/wred_sum(ts);
  for (int j = lane; j < deg; j += 64){
    int s; float a;
    if (j < CAP){ s = sbuf[wave][j]; a = ebuf[wave][j]; }
    else { s = csr[beg+j]; a = __expf(lrelu(s2s[s] + sd)); }
    atomicAdd(&wsrc[s], a * inv);
  }
}

// ---------------- weighted hnei sum (coalesced): acc256[dim] = sum_n w[n]*hnei[n][dim]
__global__ __launch_bounds__(256) void k_hsum(const uint_t* __restrict__ hneib,
    const float* __restrict__ wsrc, float* __restrict__ acc256, int N)
{
  __shared__ float pr[512];
  const int t = threadIdx.x;
  const int h2 = t >> 7, p = t & 127;
  float a0 = 0.f, a1 = 0.f;
  const int step = gridDim.x * 2;
  for (int n = blockIdx.x*2 + h2; n < N; n += step){
    float wn = wsrc[n];
    uint_t u = hneib[(size_t)n*128 + p];
    a0 += wn * b2f_lo(u);
    a1 += wn * b2f_hi(u);
  }
  pr[h2*256 + 2*p]     = a0;
  pr[h2*256 + 2*p + 1] = a1;
  __syncthreads();
  float v = pr[t] + pr[256 + t];
  int pp = t >> 1;
  int d = (pp >> 5)*64 + 2*(pp & 31) + (t & 1);
  atomicAdd(&acc256[d], v);
}

// ---------------- fractal: accFrac[s*128+k] = sum_n h[fcm[n,s]][k]  (f32, float4 rows)
__global__ __launch_bounds__(256) void k_frac(const float* __restrict__ h,
    const int* __restrict__ fcm, float* __restrict__ accFrac, int N)
{
  __shared__ float red[8][384];
  const int tid = threadIdx.x;
  const int wave = tid >> 6, lane = tid & 63;
  const int g = lane >> 5, li = lane & 31;          // group of 32 lanes = one node stream
  const int stream0 = blockIdx.x*8 + wave*2 + g;
  const int step = gridDim.x * 8;
  float4 a0 = {0,0,0,0}, a1 = {0,0,0,0}, a2 = {0,0,0,0};
  for (int n = stream0; n < N; n += step){
    int i0 = fcm[n*3], i1 = fcm[n*3+1], i2 = fcm[n*3+2];
    float4 v0 = *(const float4*)&h[(size_t)i0*128 + li*4];
    float4 v1 = *(const float4*)&h[(size_t)i1*128 + li*4];
    float4 v2 = *(const float4*)&h[(size_t)i2*128 + li*4];
    a0.x += v0.x; a0.y += v0.y; a0.z += v0.z; a0.w += v0.w;
    a1.x += v1.x; a1.y += v1.y; a1.z += v1.z; a1.w += v1.w;
    a2.x += v2.x; a2.y += v2.y; a2.z += v2.z; a2.w += v2.w;
  }
  const int w8 = wave*2 + g;
  *(float4*)&red[w8][0*128 + li*4] = a0;
  *(float4*)&red[w8][1*128 + li*4] = a1;
  *(float4*)&red[w8][2*128 + li*4] = a2;
  __syncthreads();
  for (int i = tid; i < 384; i += 256){
    float v = 0.f;
#pragma unroll
    for (int w = 0; w < 8; w++) v += red[w][i];
    atomicAdd(&accFrac[i], v);
  }
}

// ---------------- finalize: mean-nei via (acc256/N)@W2^T (f32), frac chain, fc2
__global__ __launch_bounds__(256) void k_finalize(const float* __restrict__ acc256,
    const float* __restrict__ accFrac, const float* __restrict__ W2,
    const float* __restrict__ frw, const float* __restrict__ frf,
    const float* __restrict__ fc2, float* __restrict__ out, float invN)
{
  __shared__ float mh[256], nei[64], g[384], mm[192], hfrac[64];
  int t = threadIdx.x;
  mh[t] = acc256[t] * invN;
  for (int i = t; i < 384; i += 256) g[i] = accFrac[i] * invN;
  __syncthreads();
  if (t < 64){
    float s = 0.f;
    for (int k = 0; k < 256; k++) s += W2[t*256 + k] * mh[k];
    nei[t] = s;
  }
  for (int i = t; i < 192; i += 256){
    int s = i >> 6, d = i & 63;
    const float* w = frw + (size_t)(s*64 + d)*128;
    const float* gs = g + s*128;
    float sum = 0.f;
    for (int k = 0; k < 128; k++) sum += gs[k]*w[k];
    mm[i] = sum;
  }
  __syncthreads();
  if (t < 64){
    float s = 0.f;
    for (int k = 0; k < 192; k++) s += mm[k]*frf[t*192 + k];
    hfrac[t] = s;
  }
  __syncthreads();
  if (t < 64){
    float o = 0.f;
    for (int k = 0; k < 64; k++)
      o += fc2[t*128 + k]*nei[k] + fc2[t*128 + 64 + k]*hfrac[k];
    out[t] = o;
  }
}

extern "C" void kernel_launch(void* const* d_in, const int* in_sizes, int n_in,
                              void* d_out, int out_size, void* d_ws, size_t ws_size,
                              hipStream_t stream)
{
  const float* h    = (const float*)d_in[0];
  const int*   srcI = (const int*)  d_in[1];
  const int*   dstI = (const int*)  d_in[2];
  const int*   fcm  = (const int*)  d_in[3];
  const float* l1fc = (const float*)d_in[4];
  const float* l1at = (const float*)d_in[5];
  const float* l2fc = (const float*)d_in[6];
  const float* l2at = (const float*)d_in[7];
  const float* frw  = (const float*)d_in[8];
  const float* frf  = (const float*)d_in[9];
  const float* fc2  = (const float*)d_in[10];
  float* out = (float*)d_out;
  (void)n_in; (void)out_size; (void)ws_size;

  const int N = in_sizes[0] / 128;
  const int E = in_sizes[1];
  const int B = (N + 256) / 256;     // ceil((N+1)/256) so rowptr[N] is covered
  const int PAD = B * 256;

  char* w = (char*)d_ws;
  size_t off = 0;
  auto alloc = [&](size_t bytes) -> char* {
    char* p = w + off; off = (off + bytes + 255) & ~(size_t)255; return p;
  };
  uint2*  zb    = (uint2*) alloc((size_t)N*64*8);    // 51.2 MB packed bf16 z
  uint_t* hneib = (uint_t*)alloc((size_t)N*128*4);   // 51.2 MB packed bf16 hnei
  float* s1s  = (float*)alloc((size_t)N*4*4);
  float* s1d  = (float*)alloc((size_t)N*4*4);
  float* s2s  = (float*)alloc((size_t)N*4);
  float* s2d  = (float*)alloc((size_t)N*4);
  // ---- zeroed region (one memset): deg, wsrc, acc256, accFrac
  int*   deg     = (int*)  alloc((size_t)PAD*4);
  float* wsrc    = (float*)alloc((size_t)N*4);
  float* acc256  = (float*)alloc(256*4);
  float* accFrac = (float*)alloc(384*4);
  const size_t zbytes = (size_t)((char*)accFrac + 384*4 - (char*)deg);
  // ---- rest
  int*   rowptr = (int*)alloc((size_t)PAD*4);
  int*   cursor = (int*)alloc((size_t)PAD*4);
  int*   part   = (int*)alloc(512*4);
  int*   csr    = (int*)alloc((size_t)E*4);
  ushort_t* w1bp = (ushort_t*)alloc(34816*2);   // 16 z-tiles + 1 score tile
  float* v2     = (float*)alloc(512*4);

  hipMemsetAsync(deg, 0, zbytes, stream);

  hipLaunchKernelGGL(k_wpack,   dim3(130),           dim3(256), 0, stream,
                     l1fc, l2fc, l1at, l2at, w1bp, v2);
  hipLaunchKernelGGL(k_hist,    dim3((E+255)/256),   dim3(256), 0, stream, dstI, deg, E);
  hipLaunchKernelGGL(k_scan1,   dim3(B),             dim3(256), 0, stream, deg, part);
  hipLaunchKernelGGL(k_scan2,   dim3(1),             dim3(512), 0, stream, part, B);
  hipLaunchKernelGGL(k_scan3,   dim3(B),             dim3(256), 0, stream, deg, part, rowptr, cursor);
  hipLaunchKernelGGL(k_scatter, dim3((E+255)/256),   dim3(256), 0, stream, srcI, dstI, cursor, csr, E);
  hipLaunchKernelGGL(k_gemm1m,  dim3((N+127)/128),   dim3(512), 0, stream,
                     h, w1bp, zb, s1s, s1d, N);
  hipLaunchKernelGGL(k_gat1,    dim3((N+3)/4),       dim3(256), 0, stream,
                     zb, s1s, s1d, rowptr, csr, v2, hneib, s2s, s2d, N);
  hipLaunchKernelGGL(k_aw2,     dim3((N+3)/4),       dim3(256), 0, stream,
                     s2s, s2d, rowptr, csr, wsrc, N);
  hipLaunchKernelGGL(k_hsum,    dim3(608),           dim3(256), 0, stream,
                     hneib, wsrc, acc256, N);
  hipLaunchKernelGGL(k_frac,    dim3(1024),          dim3(256), 0, stream, h, fcm, accFrac, N);
  hipLaunchKernelGGL(k_finalize,dim3(1),             dim3(256), 0, stream,
                     acc256, accFrac, l2fc, frw, frf, fc2, out, 1.0f/(float)N);
}

// Round 11
// 626.507 us; speedup vs baseline: 1.2107x; 1.0547x over previous
//
#include <hip/hip_runtime.h>
#include <math.h>

// GAT pipeline. Layer2 collapsed: mean(GAT2) = (Σ_s w_s hnei[s])@W2^T with
// w_s = Σ_{e:src=s} α_e (CSR wave-per-dst). s2 scores fused in gat1 (v2=W2^T a2).
// z stored as OCP fp8 e4m3 (values ~N(0,1), in-range; softmax scores stay f32
// via the split-A MFMA score tile) -> gather bytes halved + pk_cvt decode.

#define CAP 128   // per-wave LDS edge cache; deg>CAP falls back to recompute

typedef unsigned int  uint_t;
typedef unsigned short ushort_t;
typedef __attribute__((ext_vector_type(8))) short short8;
typedef __attribute__((ext_vector_type(4))) float floatx4;
typedef __attribute__((ext_vector_type(2))) float floatx2;

__device__ __forceinline__ float wred_sum(float v){
#pragma unroll
  for (int o = 1; o < 64; o <<= 1) v += __shfl_xor(v, o, 64);
  return v;
}
__device__ __forceinline__ float lrelu(float x){ return x >= 0.f ? x : 0.01f*x; }
__device__ __forceinline__ ushort_t f2b(float f){
  uint_t u = __float_as_uint(f);
  u = (u + 0x7FFFu + ((u >> 16) & 1u)) >> 16;   // RNE
  return (ushort_t)u;
}
__device__ __forceinline__ float b2f_lo(uint_t w){ return __uint_as_float(w << 16); }
__device__ __forceinline__ float b2f_hi(uint_t w){ return __uint_as_float(w & 0xFFFF0000u); }

// ---------------- pack: W1 tiles (bx 0..127), layer1 score tile (bx 128),
// v2 = [W2^T a2_src ; W2^T a2_dst] f32 (bx 129)
__global__ void k_wpack(const float* __restrict__ W1, const float* __restrict__ W2,
                        const float* __restrict__ a1, const float* __restrict__ a2,
                        ushort_t* __restrict__ w1bp, float* __restrict__ v2){
  __shared__ float v[8][128];
  const int bx = blockIdx.x, t = threadIdx.x;
  if (bx < 128){
    int idx = bx*256 + t;
    int j = idx & 7, lane = (idx >> 3) & 63, ks = (idx >> 9) & 3, tt = idx >> 11;
    int n = tt*16 + (lane & 15), k = ks*32 + (lane >> 4)*8 + j;
    w1bp[idx] = f2b(W1[n*128 + k]);
  } else if (bx == 128){
    // layer1 score tile: col 0..3 = src score vec per head, 4..7 = dst
    for (int o = t; o < 1024; o += 256){
      int col = o >> 7, k = o & 127, hh = col & 3, off = (col >> 2)*64;
      float s = 0.f;
      for (int n = 0; n < 64; n++) s += a1[hh*128 + off + n] * W1[(hh*64 + n)*128 + k];
      v[col][k] = s;
    }
    __syncthreads();
    for (int idx = t; idx < 2048; idx += 256){
      int j = idx & 7, lane = (idx >> 3) & 63, ks = idx >> 9;
      int col = lane & 15, k = ks*32 + (lane >> 4)*8 + j;
      w1bp[32768 + idx] = (col < 8) ? f2b(v[col][k]) : (ushort_t)0;
    }
  } else {
    // v2[k] = sum_j W2[j][k]*a2[j]; v2[256+k] = sum_j W2[j][k]*a2[64+j]
    float s0 = 0.f, s1 = 0.f;
    for (int j = 0; j < 64; j++){
      float wjk = W2[j*256 + t];
      s0 += wjk * a2[j];
      s1 += wjk * a2[64 + j];
    }
    v2[t] = s0; v2[256 + t] = s1;
  }
}

// ---------------- GEMM1 (MFMA, LDS-staged B): z8 fp8 + layer1 scores
// z-tiles: single bf16 A (output fp8-rounded anyway); score tile: split hi+lo A.
__global__ __launch_bounds__(512) void k_gemm1m(const float* __restrict__ h,
    const ushort_t* __restrict__ w1bp,
    uint_t* __restrict__ z8, float* __restrict__ s1s, float* __restrict__ s1d, int N)
{
  __shared__ __align__(16) ushort_t ldsB[34816];   // 69,632 B
  const int tid = threadIdx.x;
  {
    const uint4* src = (const uint4*)w1bp;
    uint4* dst = (uint4*)ldsB;
    for (int i = tid; i < 4352; i += 512) dst[i] = src[i];
  }
  __syncthreads();
  const int wave = tid >> 6, lane = tid & 63;
  const int quad = lane >> 4, l16 = lane & 15;
  const int row0 = blockIdx.x*128 + wave*16;
  if (row0 >= N) return;
  const int ar = (row0 + l16 < N) ? (row0 + l16) : (N - 1);   // clamp; dups discarded
  floatx4 c[17];
#pragma unroll
  for (int t = 0; t < 17; t++) c[t] = (floatx4){0.f,0.f,0.f,0.f};
#pragma unroll
  for (int ks = 0; ks < 4; ks++){
    const float* ap = &h[(size_t)ar*128 + ks*32 + quad*8];
    float4 v0 = *(const float4*)ap;
    float4 v1 = *(const float4*)(ap + 4);
    float vv[8] = {v0.x,v0.y,v0.z,v0.w,v1.x,v1.y,v1.z,v1.w};
    short8 ahi, alo;
#pragma unroll
    for (int j = 0; j < 8; j++){
      ushort_t hb = f2b(vv[j]);
      float hf = __uint_as_float((uint_t)hb << 16);
      ahi[j] = (short)hb;
      alo[j] = (short)f2b(vv[j] - hf);
    }
#pragma unroll
    for (int t = 0; t < 17; t++){
      short8 b = *(const short8*)&ldsB[(size_t)((t*4 + ks)*64 + lane)*8];
      c[t] = __builtin_amdgcn_mfma_f32_16x16x32_bf16(ahi, b, c[t], 0, 0, 0);
    }
    // lo-correction only for the score tile (t=16)
    {
      short8 b = *(const short8*)&ldsB[(size_t)((16*4 + ks)*64 + lane)*8];
      c[16] = __builtin_amdgcn_mfma_f32_16x16x32_bf16(alo, b, c[16], 0, 0, 0);
    }
  }
#pragma unroll
  for (int i = 0; i < 4; i++){
    const int r = row0 + quad*4 + i;
    if (r >= N) continue;
#pragma unroll
    for (int m = 0; m < 4; m++){
      // dword at dim d=m*16+l16: bytes = heads {0,1,2,3}, fp8 e4m3
      int u = 0;
      u = __builtin_amdgcn_cvt_pk_fp8_f32(c[0*4+m][i], c[1*4+m][i], u, false);
      u = __builtin_amdgcn_cvt_pk_fp8_f32(c[2*4+m][i], c[3*4+m][i], u, true);
      z8[(size_t)r*64 + m*16 + l16] = (uint_t)u;
    }
    const float sv = c[16][i];
    if (l16 < 4) s1s[r*4 + l16] = sv;
    else if (l16 < 8) s1d[r*4 + (l16 - 4)] = sv;
  }
}

// ---------------- CSR build
__global__ void k_hist(const int* __restrict__ d, int* __restrict__ deg, int E){
  int i = blockIdx.x*256 + threadIdx.x;
  if (i < E) atomicAdd(&deg[d[i]], 1);
}
__global__ __launch_bounds__(256) void k_scan1(const int* __restrict__ deg, int* __restrict__ part){
  __shared__ int tmp[256];
  int t = threadIdx.x;
  tmp[t] = deg[blockIdx.x*256 + t];
  __syncthreads();
  for (int off = 128; off > 0; off >>= 1){
    if (t < off) tmp[t] += tmp[t+off];
    __syncthreads();
  }
  if (t == 0) part[blockIdx.x] = tmp[0];
}
__global__ __launch_bounds__(512) void k_scan2(int* __restrict__ part, int B){
  __shared__ int tmp[512];
  int t = threadIdx.x;
  int v = (t < B) ? part[t] : 0;
  tmp[t] = v; __syncthreads();
  for (int off = 1; off < 512; off <<= 1){
    int x = (t >= off) ? tmp[t-off] : 0;
    __syncthreads();
    tmp[t] += x;
    __syncthreads();
  }
  if (t < B) part[t] = tmp[t] - v;   // exclusive
}
__global__ __launch_bounds__(256) void k_scan3(const int* __restrict__ deg, const int* __restrict__ part,
    int* __restrict__ rowptr, int* __restrict__ cursor){
  __shared__ int tmp[256];
  int t = threadIdx.x, i = blockIdx.x*256 + t;
  int v = deg[i];
  tmp[t] = v; __syncthreads();
  for (int off = 1; off < 256; off <<= 1){
    int x = (t >= off) ? tmp[t-off] : 0;
    __syncthreads();
    tmp[t] += x;
    __syncthreads();
  }
  int excl = tmp[t] - v + part[blockIdx.x];
  rowptr[i] = excl; cursor[i] = excl;
}
__global__ void k_scatter(const int* __restrict__ s, const int* __restrict__ d,
    int* __restrict__ cursor, int* __restrict__ csr, int E){
  int i = blockIdx.x*256 + threadIdx.x;
  if (i < E){
    int p = atomicAdd(&cursor[d[i]], 1);
    csr[p] = s[i];
  }
}

// ---------------- layer1 GAT aggregation + ELU -> hneib bf16 + fused layer2 scores
__global__ __launch_bounds__(256) void k_gat1(
    const uint_t* __restrict__ z8, const float* __restrict__ s1src, const float* __restrict__ s1dst,
    const int* __restrict__ rowptr, const int* __restrict__ csr, const float* __restrict__ v2,
    uint_t* __restrict__ hneib, float* __restrict__ s2s, float* __restrict__ s2d, int N)
{
  __shared__ int   sbuf[4][CAP];
  __shared__ __align__(16) float4 ebuf[4][CAP];
  __shared__ float v2s[512];
  const int tid = threadIdx.x;
  v2s[tid] = v2[tid];
  v2s[tid + 256] = v2[tid + 256];
  __syncthreads();
  const int wave = tid >> 6, lane = tid & 63;
  const int dst = blockIdx.x*4 + wave;
  if (dst >= N) return;
  const int beg = rowptr[dst];
  const int deg = rowptr[dst+1] - beg;
  const float4 sd = *(const float4*)&s1dst[dst*4];
  float t0=0.f,t1=0.f,t2=0.f,t3=0.f;
  for (int j = lane; j < deg; j += 64){
    int s = csr[beg+j];
    float4 sv = *(const float4*)&s1src[s*4];
    float4 a;
    a.x = __expf(lrelu(sv.x+sd.x)); a.y = __expf(lrelu(sv.y+sd.y));
    a.z = __expf(lrelu(sv.z+sd.z)); a.w = __expf(lrelu(sv.w+sd.w));
    if (j < CAP){ sbuf[wave][j] = s; ebuf[wave][j] = a; }
    t0 += a.x; t1 += a.y; t2 += a.z; t3 += a.w;
  }
  const float inv[4] = {1.f/wred_sum(t0), 1.f/wred_sum(t1), 1.f/wred_sum(t2), 1.f/wred_sum(t3)};
  // pass B: 2 edges/iter; eh = edge parity, li covers dims 2li, 2li+1 (x4 heads)
  const int eh = lane >> 5, li = lane & 31;
  float acc[2][4] = {};
  int jj = 0;
  if (deg <= CAP){
    for (; jj + 2 <= deg; jj += 2){
      const int j = jj + eh;
      int s = sbuf[wave][j]; float4 al = ebuf[wave][j];
      uint2 u = *((const uint2*)(z8 + (size_t)s*64) + li);
      floatx2 p0 = __builtin_amdgcn_cvt_pk_f32_fp8(u.x, false);  // dim 2li,   heads 0,1
      floatx2 p1 = __builtin_amdgcn_cvt_pk_f32_fp8(u.x, true);   // dim 2li,   heads 2,3
      floatx2 p2 = __builtin_amdgcn_cvt_pk_f32_fp8(u.y, false);  // dim 2li+1, heads 0,1
      floatx2 p3 = __builtin_amdgcn_cvt_pk_f32_fp8(u.y, true);   // dim 2li+1, heads 2,3
      acc[0][0] += al.x * p0.x;
      acc[0][1] += al.y * p0.y;
      acc[0][2] += al.z * p1.x;
      acc[0][3] += al.w * p1.y;
      acc[1][0] += al.x * p2.x;
      acc[1][1] += al.y * p2.y;
      acc[1][2] += al.z * p3.x;
      acc[1][3] += al.w * p3.y;
    }
    if (jj < deg && eh == 0){
      int s = sbuf[wave][jj]; float4 al = ebuf[wave][jj];
      uint2 u = *((const uint2*)(z8 + (size_t)s*64) + li);
      floatx2 p0 = __builtin_amdgcn_cvt_pk_f32_fp8(u.x, false);
      floatx2 p1 = __builtin_amdgcn_cvt_pk_f32_fp8(u.x, true);
      floatx2 p2 = __builtin_amdgcn_cvt_pk_f32_fp8(u.y, false);
      floatx2 p3 = __builtin_amdgcn_cvt_pk_f32_fp8(u.y, true);
      acc[0][0] += al.x * p0.x;
      acc[0][1] += al.y * p0.y;
      acc[0][2] += al.z * p1.x;
      acc[0][3] += al.w * p1.y;
      acc[1][0] += al.x * p2.x;
      acc[1][1] += al.y * p2.y;
      acc[1][2] += al.z * p3.x;
      acc[1][3] += al.w * p3.y;
    }
  } else {
    for (; jj < deg; jj += 2){
      const int j = jj + eh;
      const bool v = j < deg;
      const int jc = v ? j : jj;
      int s; float4 al;
      if (jc < CAP){ s = sbuf[wave][jc]; al = ebuf[wave][jc]; }
      else {
        s = csr[beg+jc];
        float4 sv = *(const float4*)&s1src[s*4];
        al.x = __expf(lrelu(sv.x+sd.x)); al.y = __expf(lrelu(sv.y+sd.y));
        al.z = __expf(lrelu(sv.z+sd.z)); al.w = __expf(lrelu(sv.w+sd.w));
      }
      if (!v){ al.x=0.f; al.y=0.f; al.z=0.f; al.w=0.f; }
      uint2 u = *((const uint2*)(z8 + (size_t)s*64) + li);
      floatx2 p0 = __builtin_amdgcn_cvt_pk_f32_fp8(u.x, false);
      floatx2 p1 = __builtin_amdgcn_cvt_pk_f32_fp8(u.x, true);
      floatx2 p2 = __builtin_amdgcn_cvt_pk_f32_fp8(u.y, false);
      floatx2 p3 = __builtin_amdgcn_cvt_pk_f32_fp8(u.y, true);
      acc[0][0] += al.x * p0.x;
      acc[0][1] += al.y * p0.y;
      acc[0][2] += al.z * p1.x;
      acc[0][3] += al.w * p1.y;
      acc[1][0] += al.x * p2.x;
      acc[1][1] += al.y * p2.y;
      acc[1][2] += al.z * p3.x;
      acc[1][3] += al.w * p3.y;
    }
  }
#pragma unroll
  for (int k = 0; k < 2; k++)
#pragma unroll
    for (int hh = 0; hh < 4; hh++) acc[k][hh] += __shfl_xor(acc[k][hh], 32, 64);
  // ELU + fused s2 score dot (half0 = src vec, half1 = dst vec)
  const float* vv = &v2s[eh*256];
  float p = 0.f;
#pragma unroll
  for (int hh = 0; hh < 4; hh++){
    float e0 = acc[0][hh]*inv[hh]; e0 = e0 > 0.f ? e0 : expm1f(e0);
    float e1 = acc[1][hh]*inv[hh]; e1 = e1 > 0.f ? e1 : expm1f(e1);
    p += e0 * vv[hh*64 + 2*li] + e1 * vv[hh*64 + 2*li + 1];
    if (eh == 0)
      hneib[(size_t)dst*128 + hh*32 + li] = (uint_t)f2b(e0) | ((uint_t)f2b(e1) << 16);
  }
#pragma unroll
  for (int o = 1; o < 32; o <<= 1) p += __shfl_xor(p, o, 64);
  if (lane == 0)  s2s[dst] = p;
  if (lane == 32) s2d[dst] = p;
}

// ---------------- layer2 alpha-weights: wave per dst over CSR; one atomic per edge
__global__ __launch_bounds__(256) void k_aw2(
    const float* __restrict__ s2s, const float* __restrict__ s2d,
    const int* __restrict__ rowptr, const int* __restrict__ csr,
    float* __restrict__ wsrc, int N)
{
  __shared__ int   sbuf[4][CAP];
  __shared__ float ebuf[4][CAP];
  const int wave = threadIdx.x >> 6, lane = threadIdx.x & 63;
  const int dst = blockIdx.x*4 + wave;
  if (dst >= N) return;
  const int beg = rowptr[dst], deg = rowptr[dst+1] - beg;
  const float sd = s2d[dst];
  float ts = 0.f;
  for (int j = lane; j < deg; j += 64){
    int s = csr[beg+j];
    float a = __expf(lrelu(s2s[s] + sd));
    if (j < CAP){ sbuf[wave][j] = s; ebuf[wave][j] = a; }
    ts += a;
  }
  const float inv = 1.f/wred_sum(ts);
  for (int j = lane; j < deg; j += 64){
    int s; float a;
    if (j < CAP){ s = sbuf[wave][j]; a = ebuf[wave][j]; }
    else { s = csr[beg+j]; a = __expf(lrelu(s2s[s] + sd)); }
    atomicAdd(&wsrc[s], a * inv);
  }
}

// ---------------- weighted hnei sum (coalesced): acc256[dim] = sum_n w[n]*hnei[n][dim]
__global__ __launch_bounds__(256) void k_hsum(const uint_t* __restrict__ hneib,
    const float* __restrict__ wsrc, float* __restrict__ acc256, int N)
{
  __shared__ float pr[512];
  const int t = threadIdx.x;
  const int h2 = t >> 7, p = t & 127;
  float a0 = 0.f, a1 = 0.f;
  const int step = gridDim.x * 2;
  for (int n = blockIdx.x*2 + h2; n < N; n += step){
    float wn = wsrc[n];
    uint_t u = hneib[(size_t)n*128 + p];
    a0 += wn * b2f_lo(u);
    a1 += wn * b2f_hi(u);
  }
  pr[h2*256 + 2*p]     = a0;
  pr[h2*256 + 2*p + 1] = a1;
  __syncthreads();
  float v = pr[t] + pr[256 + t];
  int pp = t >> 1;
  int d = (pp >> 5)*64 + 2*(pp & 31) + (t & 1);
  atomicAdd(&acc256[d], v);
}

// ---------------- fractal: accFrac[s*128+k] = sum_n h[fcm[n,s]][k]  (f32, float4 rows)
__global__ __launch_bounds__(256) void k_frac(const float* __restrict__ h,
    const int* __restrict__ fcm, float* __restrict__ accFrac, int N)
{
  __shared__ float red[8][384];
  const int tid = threadIdx.x;
  const int wave = tid >> 6, lane = tid & 63;
  const int g = lane >> 5, li = lane & 31;          // group of 32 lanes = one node stream
  const int stream0 = blockIdx.x*8 + wave*2 + g;
  const int step = gridDim.x * 8;
  float4 a0 = {0,0,0,0}, a1 = {0,0,0,0}, a2 = {0,0,0,0};
  for (int n = stream0; n < N; n += step){
    int i0 = fcm[n*3], i1 = fcm[n*3+1], i2 = fcm[n*3+2];
    float4 v0 = *(const float4*)&h[(size_t)i0*128 + li*4];
    float4 v1 = *(const float4*)&h[(size_t)i1*128 + li*4];
    float4 v2 = *(const float4*)&h[(size_t)i2*128 + li*4];
    a0.x += v0.x; a0.y += v0.y; a0.z += v0.z; a0.w += v0.w;
    a1.x += v1.x; a1.y += v1.y; a1.z += v1.z; a1.w += v1.w;
    a2.x += v2.x; a2.y += v2.y; a2.z += v2.z; a2.w += v2.w;
  }
  const int w8 = wave*2 + g;
  *(float4*)&red[w8][0*128 + li*4] = a0;
  *(float4*)&red[w8][1*128 + li*4] = a1;
  *(float4*)&red[w8][2*128 + li*4] = a2;
  __syncthreads();
  for (int i = tid; i < 384; i += 256){
    float v = 0.f;
#pragma unroll
    for (int w = 0; w < 8; w++) v += red[w][i];
    atomicAdd(&accFrac[i], v);
  }
}

// ---------------- finalize: mean-nei via (acc256/N)@W2^T (f32), frac chain, fc2
__global__ __launch_bounds__(256) void k_finalize(const float* __restrict__ acc256,
    const float* __restrict__ accFrac, const float* __restrict__ W2,
    const float* __restrict__ frw, const float* __restrict__ frf,
    const float* __restrict__ fc2, float* __restrict__ out, float invN)
{
  __shared__ float mh[256], nei[64], g[384], mm[192], hfrac[64];
  int t = threadIdx.x;
  mh[t] = acc256[t] * invN;
  for (int i = t; i < 384; i += 256) g[i] = accFrac[i] * invN;
  __syncthreads();
  if (t < 64){
    float s = 0.f;
    for (int k = 0; k < 256; k++) s += W2[t*256 + k] * mh[k];
    nei[t] = s;
  }
  for (int i = t; i < 192; i += 256){
    int s = i >> 6, d = i & 63;
    const float* w = frw + (size_t)(s*64 + d)*128;
    const float* gs = g + s*128;
    float sum = 0.f;
    for (int k = 0; k < 128; k++) sum += gs[k]*w[k];
    mm[i] = sum;
  }
  __syncthreads();
  if (t < 64){
    float s = 0.f;
    for (int k = 0; k < 192; k++) s += mm[k]*frf[t*192 + k];
    hfrac[t] = s;
  }
  __syncthreads();
  if (t < 64){
    float o = 0.f;
    for (int k = 0; k < 64; k++)
      o += fc2[t*128 + k]*nei[k] + fc2[t*128 + 64 + k]*hfrac[k];
    out[t] = o;
  }
}

extern "C" void kernel_launch(void* const* d_in, const int* in_sizes, int n_in,
                              void* d_out, int out_size, void* d_ws, size_t ws_size,
                              hipStream_t stream)
{
  const float* h    = (const float*)d_in[0];
  const int*   srcI = (const int*)  d_in[1];
  const int*   dstI = (const int*)  d_in[2];
  const int*   fcm  = (const int*)  d_in[3];
  const float* l1fc = (const float*)d_in[4];
  const float* l1at = (const float*)d_in[5];
  const float* l2fc = (const float*)d_in[6];
  const float* l2at = (const float*)d_in[7];
  const float* frw  = (const float*)d_in[8];
  const float* frf  = (const float*)d_in[9];
  const float* fc2  = (const float*)d_in[10];
  float* out = (float*)d_out;
  (void)n_in; (void)out_size; (void)ws_size;

  const int N = in_sizes[0] / 128;
  const int E = in_sizes[1];
  const int B = (N + 256) / 256;     // ceil((N+1)/256) so rowptr[N] is covered
  const int PAD = B * 256;

  char* w = (char*)d_ws;
  size_t off = 0;
  auto alloc = [&](size_t bytes) -> char* {
    char* p = w + off; off = (off + bytes + 255) & ~(size_t)255; return p;
  };
  uint_t* z8    = (uint_t*)alloc((size_t)N*64*4);    // 25.6 MB fp8 z (4 heads/dword)
  uint_t* hneib = (uint_t*)alloc((size_t)N*128*4);   // 51.2 MB packed bf16 hnei
  float* s1s  = (float*)alloc((size_t)N*4*4);
  float* s1d  = (float*)alloc((size_t)N*4*4);
  float* s2s  = (float*)alloc((size_t)N*4);
  float* s2d  = (float*)alloc((size_t)N*4);
  // ---- zeroed region (one memset): deg, wsrc, acc256, accFrac
  int*   deg     = (int*)  alloc((size_t)PAD*4);
  float* wsrc    = (float*)alloc((size_t)N*4);
  float* acc256  = (float*)alloc(256*4);
  float* accFrac = (float*)alloc(384*4);
  const size_t zbytes = (size_t)((char*)accFrac + 384*4 - (char*)deg);
  // ---- rest
  int*   rowptr = (int*)alloc((size_t)PAD*4);
  int*   cursor = (int*)alloc((size_t)PAD*4);
  int*   part   = (int*)alloc(512*4);
  int*   csr    = (int*)alloc((size_t)E*4);
  ushort_t* w1bp = (ushort_t*)alloc(34816*2);   // 16 z-tiles + 1 score tile
  float* v2     = (float*)alloc(512*4);

  hipMemsetAsync(deg, 0, zbytes, stream);

  hipLaunchKernelGGL(k_wpack,   dim3(130),           dim3(256), 0, stream,
                     l1fc, l2fc, l1at, l2at, w1bp, v2);
  hipLaunchKernelGGL(k_hist,    dim3((E+255)/256),   dim3(256), 0, stream, dstI, deg, E);
  hipLaunchKernelGGL(k_scan1,   dim3(B),             dim3(256), 0, stream, deg, part);
  hipLaunchKernelGGL(k_scan2,   dim3(1),             dim3(512), 0, stream, part, B);
  hipLaunchKernelGGL(k_scan3,   dim3(B),             dim3(256), 0, stream, deg, part, rowptr, cursor);
  hipLaunchKernelGGL(k_scatter, dim3((E+255)/256),   dim3(256), 0, stream, srcI, dstI, cursor, csr, E);
  hipLaunchKernelGGL(k_gemm1m,  dim3((N+127)/128),   dim3(512), 0, stream,
                     h, w1bp, z8, s1s, s1d, N);
  hipLaunchKernelGGL(k_gat1,    dim3((N+3)/4),       dim3(256), 0, stream,
                     z8, s1s, s1d, rowptr, csr, v2, hneib, s2s, s2d, N);
  hipLaunchKernelGGL(k_aw2,     dim3((N+3)/4),       dim3(256), 0, stream,
                     s2s, s2d, rowptr, csr, wsrc, N);
  hipLaunchKernelGGL(k_hsum,    dim3(608),           dim3(256), 0, stream,
                     hneib, wsrc, acc256, N);
  hipLaunchKernelGGL(k_frac,    dim3(1024),          dim3(256), 0, stream, h, fcm, accFrac, N);
  hipLaunchKernelGGL(k_finalize,dim3(1),             dim3(256), 0, stream,
                     acc256, accFrac, l2fc, frw, frf, fc2, out, 1.0f/(float)N);
}

// Round 12
// 614.738 us; speedup vs baseline: 1.2339x; 1.0191x over previous
//
#include <hip/hip_runtime.h>
#include <math.h>

// GAT pipeline. Layer2 collapsed (w_s = Σ α over src edges); z in fp8 e4m3;
// MFMA GEMM1 with f32 score tile. NEW: block-role mega-kernel fuses
// gemm1m + scatter + frac in ONE launch so the latency-bound CSR scatter
// (125us, 0.3% VALU, 16x write-amplified) overlaps the compute-bound GEMM.

#define CAP 128

typedef unsigned int  uint_t;
typedef unsigned short ushort_t;
typedef __attribute__((ext_vector_type(8))) short short8;
typedef __attribute__((ext_vector_type(4))) float floatx4;
typedef __attribute__((ext_vector_type(2))) float floatx2;

__device__ __forceinline__ float wred_sum(float v){
#pragma unroll
  for (int o = 1; o < 64; o <<= 1) v += __shfl_xor(v, o, 64);
  return v;
}
__device__ __forceinline__ float lrelu(float x){ return x >= 0.f ? x : 0.01f*x; }
__device__ __forceinline__ ushort_t f2b(float f){
  uint_t u = __float_as_uint(f);
  u = (u + 0x7FFFu + ((u >> 16) & 1u)) >> 16;   // RNE
  return (ushort_t)u;
}
__device__ __forceinline__ float b2f_lo(uint_t w){ return __uint_as_float(w << 16); }
__device__ __forceinline__ float b2f_hi(uint_t w){ return __uint_as_float(w & 0xFFFF0000u); }

// ---------------- prep: wpack roles (bx 0..129) + hist grid-stride (bx >=130)
__global__ void k_prep(const float* __restrict__ W1, const float* __restrict__ W2,
                       const float* __restrict__ a1, const float* __restrict__ a2,
                       const int* __restrict__ dstI, int E,
                       ushort_t* __restrict__ w1bp, float* __restrict__ v2,
                       int* __restrict__ deg){
  __shared__ float v[8][128];
  const int bx = blockIdx.x, t = threadIdx.x;
  if (bx < 128){
    int idx = bx*256 + t;
    int j = idx & 7, lane = (idx >> 3) & 63, ks = (idx >> 9) & 3, tt = idx >> 11;
    int n = tt*16 + (lane & 15), k = ks*32 + (lane >> 4)*8 + j;
    w1bp[idx] = f2b(W1[n*128 + k]);
  } else if (bx == 128){
    for (int o = t; o < 1024; o += 256){
      int col = o >> 7, k = o & 127, hh = col & 3, off = (col >> 2)*64;
      float s = 0.f;
      for (int n = 0; n < 64; n++) s += a1[hh*128 + off + n] * W1[(hh*64 + n)*128 + k];
      v[col][k] = s;
    }
    __syncthreads();
    for (int idx = t; idx < 2048; idx += 256){
      int j = idx & 7, lane = (idx >> 3) & 63, ks = idx >> 9;
      int col = lane & 15, k = ks*32 + (lane >> 4)*8 + j;
      w1bp[32768 + idx] = (col < 8) ? f2b(v[col][k]) : (ushort_t)0;
    }
  } else if (bx == 129){
    float s0 = 0.f, s1 = 0.f;
    for (int j = 0; j < 64; j++){
      float wjk = W2[j*256 + t];
      s0 += wjk * a2[j];
      s1 += wjk * a2[64 + j];
    }
    v2[t] = s0; v2[256 + t] = s1;
  } else {
    const int nb = gridDim.x - 130;
    for (int i = (bx-130)*256 + t; i < E; i += nb*256)
      atomicAdd(&deg[dstI[i]], 1);
  }
}

// ---------------- scans
__global__ __launch_bounds__(256) void k_scan1(const int* __restrict__ deg, int* __restrict__ part){
  __shared__ int tmp[256];
  int t = threadIdx.x;
  tmp[t] = deg[blockIdx.x*256 + t];
  __syncthreads();
  for (int off = 128; off > 0; off >>= 1){
    if (t < off) tmp[t] += tmp[t+off];
    __syncthreads();
  }
  if (t == 0) part[blockIdx.x] = tmp[0];
}
__global__ __launch_bounds__(512) void k_scan2(int* __restrict__ part, int B){
  __shared__ int tmp[512];
  int t = threadIdx.x;
  int v = (t < B) ? part[t] : 0;
  tmp[t] = v; __syncthreads();
  for (int off = 1; off < 512; off <<= 1){
    int x = (t >= off) ? tmp[t-off] : 0;
    __syncthreads();
    tmp[t] += x;
    __syncthreads();
  }
  if (t < B) part[t] = tmp[t] - v;   // exclusive
}
__global__ __launch_bounds__(256) void k_scan3(const int* __restrict__ deg, const int* __restrict__ part,
    int* __restrict__ rowptr, int* __restrict__ cursor){
  __shared__ int tmp[256];
  int t = threadIdx.x, i = blockIdx.x*256 + t;
  int v = deg[i];
  tmp[t] = v; __syncthreads();
  for (int off = 1; off < 256; off <<= 1){
    int x = (t >= off) ? tmp[t-off] : 0;
    __syncthreads();
    tmp[t] += x;
    __syncthreads();
  }
  int excl = tmp[t] - v + part[blockIdx.x];
  rowptr[i] = excl; cursor[i] = excl;
}

// ---------------- MEGA: gemm1m [0,Gg) + scatter [Gg,Gg+Gs) + frac [Gg+Gs,...)
__global__ __launch_bounds__(512) void k_mega(const float* __restrict__ h,
    const ushort_t* __restrict__ w1bp,
    uint_t* __restrict__ z8, float* __restrict__ s1s, float* __restrict__ s1d, int N,
    const int* __restrict__ srcI, const int* __restrict__ dstI,
    int* __restrict__ cursor, int* __restrict__ csr, int E, int Gg, int Gs,
    const int* __restrict__ fcm, float* __restrict__ accFrac)
{
  static __shared__ __align__(16) char smem[69632];
  const int bx = blockIdx.x, tid = threadIdx.x;
  if (bx < Gg){
    // ---- GEMM1 role (512 thr, 8 wave-strips of 16 rows)
    ushort_t* ldsB = (ushort_t*)smem;
    {
      const uint4* src = (const uint4*)w1bp;
      uint4* dst = (uint4*)ldsB;
      for (int i = tid; i < 4352; i += 512) dst[i] = src[i];
    }
    __syncthreads();
    const int wave = tid >> 6, lane = tid & 63;
    const int quad = lane >> 4, l16 = lane & 15;
    const int row0 = bx*128 + wave*16;
    if (row0 >= N) return;
    const int ar = (row0 + l16 < N) ? (row0 + l16) : (N - 1);
    floatx4 c[17];
#pragma unroll
    for (int t = 0; t < 17; t++) c[t] = (floatx4){0.f,0.f,0.f,0.f};
#pragma unroll
    for (int ks = 0; ks < 4; ks++){
      const float* ap = &h[(size_t)ar*128 + ks*32 + quad*8];
      float4 v0 = *(const float4*)ap;
      float4 v1 = *(const float4*)(ap + 4);
      float vv[8] = {v0.x,v0.y,v0.z,v0.w,v1.x,v1.y,v1.z,v1.w};
      short8 ahi, alo;
#pragma unroll
      for (int j = 0; j < 8; j++){
        ushort_t hb = f2b(vv[j]);
        float hf = __uint_as_float((uint_t)hb << 16);
        ahi[j] = (short)hb;
        alo[j] = (short)f2b(vv[j] - hf);
      }
#pragma unroll
      for (int t = 0; t < 17; t++){
        short8 b = *(const short8*)&ldsB[(size_t)((t*4 + ks)*64 + lane)*8];
        c[t] = __builtin_amdgcn_mfma_f32_16x16x32_bf16(ahi, b, c[t], 0, 0, 0);
      }
      {
        short8 b = *(const short8*)&ldsB[(size_t)((16*4 + ks)*64 + lane)*8];
        c[16] = __builtin_amdgcn_mfma_f32_16x16x32_bf16(alo, b, c[16], 0, 0, 0);
      }
    }
#pragma unroll
    for (int i = 0; i < 4; i++){
      const int r = row0 + quad*4 + i;
      if (r >= N) continue;
#pragma unroll
      for (int m = 0; m < 4; m++){
        int u = 0;
        u = __builtin_amdgcn_cvt_pk_fp8_f32(c[0*4+m][i], c[1*4+m][i], u, false);
        u = __builtin_amdgcn_cvt_pk_fp8_f32(c[2*4+m][i], c[3*4+m][i], u, true);
        z8[(size_t)r*64 + m*16 + l16] = (uint_t)u;
      }
      const float sv = c[16][i];
      if (l16 < 4) s1s[r*4 + l16] = sv;
      else if (l16 < 8) s1d[r*4 + (l16 - 4)] = sv;
    }
  } else if (bx < Gg + Gs){
    // ---- scatter role
    const int i = (bx - Gg)*512 + tid;
    if (i < E){
      int p = atomicAdd(&cursor[dstI[i]], 1);
      csr[p] = srcI[i];
    }
  } else {
    // ---- frac role (512 thr -> 16 node-streams/block)
    float (*red)[384] = (float(*)[384])smem;
    const int wave = tid >> 6, lane = tid & 63;
    const int g = lane >> 5, li = lane & 31;
    const int Gf = gridDim.x - Gg - Gs;
    const int stream0 = (bx - Gg - Gs)*16 + wave*2 + g;
    const int step = Gf * 16;
    float4 a0 = {0,0,0,0}, a1 = {0,0,0,0}, a2 = {0,0,0,0};
    for (int n = stream0; n < N; n += step){
      int i0 = fcm[n*3], i1 = fcm[n*3+1], i2 = fcm[n*3+2];
      float4 v0 = *(const float4*)&h[(size_t)i0*128 + li*4];
      float4 v1 = *(const float4*)&h[(size_t)i1*128 + li*4];
      float4 v2 = *(const float4*)&h[(size_t)i2*128 + li*4];
      a0.x += v0.x; a0.y += v0.y; a0.z += v0.z; a0.w += v0.w;
      a1.x += v1.x; a1.y += v1.y; a1.z += v1.z; a1.w += v1.w;
      a2.x += v2.x; a2.y += v2.y; a2.z += v2.z; a2.w += v2.w;
    }
    const int w16 = wave*2 + g;
    *(float4*)&red[w16][0*128 + li*4] = a0;
    *(float4*)&red[w16][1*128 + li*4] = a1;
    *(float4*)&red[w16][2*128 + li*4] = a2;
    __syncthreads();
    for (int i = tid; i < 384; i += 512){
      float v = 0.f;
#pragma unroll
      for (int w = 0; w < 16; w++) v += red[w][i];
      atomicAdd(&accFrac[i], v);
    }
  }
}

// ---------------- layer1 GAT aggregation + ELU -> hneib bf16 + fused layer2 scores
__global__ __launch_bounds__(256) void k_gat1(
    const uint_t* __restrict__ z8, const float* __restrict__ s1src, const float* __restrict__ s1dst,
    const int* __restrict__ rowptr, const int* __restrict__ csr, const float* __restrict__ v2,
    uint_t* __restrict__ hneib, float* __restrict__ s2s, float* __restrict__ s2d, int N)
{
  __shared__ int   sbuf[4][CAP];
  __shared__ __align__(16) float4 ebuf[4][CAP];
  __shared__ float v2s[512];
  const int tid = threadIdx.x;
  v2s[tid] = v2[tid];
  v2s[tid + 256] = v2[tid + 256];
  __syncthreads();
  const int wave = tid >> 6, lane = tid & 63;
  const int dst = blockIdx.x*4 + wave;
  if (dst >= N) return;
  const int beg = rowptr[dst];
  const int deg = rowptr[dst+1] - beg;
  const float4 sd = *(const float4*)&s1dst[dst*4];
  float t0=0.f,t1=0.f,t2=0.f,t3=0.f;
  for (int j = lane; j < deg; j += 64){
    int s = csr[beg+j];
    float4 sv = *(const float4*)&s1src[s*4];
    float4 a;
    a.x = __expf(lrelu(sv.x+sd.x)); a.y = __expf(lrelu(sv.y+sd.y));
    a.z = __expf(lrelu(sv.z+sd.z)); a.w = __expf(lrelu(sv.w+sd.w));
    if (j < CAP){ sbuf[wave][j] = s; ebuf[wave][j] = a; }
    t0 += a.x; t1 += a.y; t2 += a.z; t3 += a.w;
  }
  const float inv[4] = {1.f/wred_sum(t0), 1.f/wred_sum(t1), 1.f/wred_sum(t2), 1.f/wred_sum(t3)};
  const int eh = lane >> 5, li = lane & 31;
  float acc[2][4] = {};
  int jj = 0;
  if (deg <= CAP){
    for (; jj + 2 <= deg; jj += 2){
      const int j = jj + eh;
      int s = sbuf[wave][j]; float4 al = ebuf[wave][j];
      uint2 u = *((const uint2*)(z8 + (size_t)s*64) + li);
      floatx2 p0 = __builtin_amdgcn_cvt_pk_f32_fp8(u.x, false);
      floatx2 p1 = __builtin_amdgcn_cvt_pk_f32_fp8(u.x, true);
      floatx2 p2 = __builtin_amdgcn_cvt_pk_f32_fp8(u.y, false);
      floatx2 p3 = __builtin_amdgcn_cvt_pk_f32_fp8(u.y, true);
      acc[0][0] += al.x * p0.x;
      acc[0][1] += al.y * p0.y;
      acc[0][2] += al.z * p1.x;
      acc[0][3] += al.w * p1.y;
      acc[1][0] += al.x * p2.x;
      acc[1][1] += al.y * p2.y;
      acc[1][2] += al.z * p3.x;
      acc[1][3] += al.w * p3.y;
    }
    if (jj < deg && eh == 0){
      int s = sbuf[wave][jj]; float4 al = ebuf[wave][jj];
      uint2 u = *((const uint2*)(z8 + (size_t)s*64) + li);
      floatx2 p0 = __builtin_amdgcn_cvt_pk_f32_fp8(u.x, false);
      floatx2 p1 = __builtin_amdgcn_cvt_pk_f32_fp8(u.x, true);
      floatx2 p2 = __builtin_amdgcn_cvt_pk_f32_fp8(u.y, false);
      floatx2 p3 = __builtin_amdgcn_cvt_pk_f32_fp8(u.y, true);
      acc[0][0] += al.x * p0.x;
      acc[0][1] += al.y * p0.y;
      acc[0][2] += al.z * p1.x;
      acc[0][3] += al.w * p1.y;
      acc[1][0] += al.x * p2.x;
      acc[1][1] += al.y * p2.y;
      acc[1][2] += al.z * p3.x;
      acc[1][3] += al.w * p3.y;
    }
  } else {
    for (; jj < deg; jj += 2){
      const int j = jj + eh;
      const bool v = j < deg;
      const int jc = v ? j : jj;
      int s; float4 al;
      if (jc < CAP){ s = sbuf[wave][jc]; al = ebuf[wave][jc]; }
      else {
        s = csr[beg+jc];
        float4 sv = *(const float4*)&s1src[s*4];
        al.x = __expf(lrelu(sv.x+sd.x)); al.y = __expf(lrelu(sv.y+sd.y));
        al.z = __expf(lrelu(sv.z+sd.z)); al.w = __expf(lrelu(sv.w+sd.w));
      }
      if (!v){ al.x=0.f; al.y=0.f; al.z=0.f; al.w=0.f; }
      uint2 u = *((const uint2*)(z8 + (size_t)s*64) + li);
      floatx2 p0 = __builtin_amdgcn_cvt_pk_f32_fp8(u.x, false);
      floatx2 p1 = __builtin_amdgcn_cvt_pk_f32_fp8(u.x, true);
      floatx2 p2 = __builtin_amdgcn_cvt_pk_f32_fp8(u.y, false);
      floatx2 p3 = __builtin_amdgcn_cvt_pk_f32_fp8(u.y, true);
      acc[0][0] += al.x * p0.x;
      acc[0][1] += al.y * p0.y;
      acc[0][2] += al.z * p1.x;
      acc[0][3] += al.w * p1.y;
      acc[1][0] += al.x * p2.x;
      acc[1][1] += al.y * p2.y;
      acc[1][2] += al.z * p3.x;
      acc[1][3] += al.w * p3.y;
    }
  }
#pragma unroll
  for (int k = 0; k < 2; k++)
#pragma unroll
    for (int hh = 0; hh < 4; hh++) acc[k][hh] += __shfl_xor(acc[k][hh], 32, 64);
  const float* vv = &v2s[eh*256];
  float p = 0.f;
#pragma unroll
  for (int hh = 0; hh < 4; hh++){
    float e0 = acc[0][hh]*inv[hh]; e0 = e0 > 0.f ? e0 : expm1f(e0);
    float e1 = acc[1][hh]*inv[hh]; e1 = e1 > 0.f ? e1 : expm1f(e1);
    p += e0 * vv[hh*64 + 2*li] + e1 * vv[hh*64 + 2*li + 1];
    if (eh == 0)
      hneib[(size_t)dst*128 + hh*32 + li] = (uint_t)f2b(e0) | ((uint_t)f2b(e1) << 16);
  }
#pragma unroll
  for (int o = 1; o < 32; o <<= 1) p += __shfl_xor(p, o, 64);
  if (lane == 0)  s2s[dst] = p;
  if (lane == 32) s2d[dst] = p;
}

// ---------------- layer2 alpha-weights: wave per dst over CSR; one atomic per edge
__global__ __launch_bounds__(256) void k_aw2(
    const float* __restrict__ s2s, const float* __restrict__ s2d,
    const int* __restrict__ rowptr, const int* __restrict__ csr,
    float* __restrict__ wsrc, int N)
{
  __shared__ int   sbuf[4][CAP];
  __shared__ float ebuf[4][CAP];
  const int wave = threadIdx.x >> 6, lane = threadIdx.x & 63;
  const int dst = blockIdx.x*4 + wave;
  if (dst >= N) return;
  const int beg = rowptr[dst], deg = rowptr[dst+1] - beg;
  const float sd = s2d[dst];
  float ts = 0.f;
  for (int j = lane; j < deg; j += 64){
    int s = csr[beg+j];
    float a = __expf(lrelu(s2s[s] + sd));
    if (j < CAP){ sbuf[wave][j] = s; ebuf[wave][j] = a; }
    ts += a;
  }
  const float inv = 1.f/wred_sum(ts);
  for (int j = lane; j < deg; j += 64){
    int s; float a;
    if (j < CAP){ s = sbuf[wave][j]; a = ebuf[wave][j]; }
    else { s = csr[beg+j]; a = __expf(lrelu(s2s[s] + sd)); }
    atomicAdd(&wsrc[s], a * inv);
  }
}

// ---------------- weighted hnei sum (coalesced)
__global__ __launch_bounds__(256) void k_hsum(const uint_t* __restrict__ hneib,
    const float* __restrict__ wsrc, float* __restrict__ acc256, int N)
{
  __shared__ float pr[512];
  const int t = threadIdx.x;
  const int h2 = t >> 7, p = t & 127;
  float a0 = 0.f, a1 = 0.f;
  const int step = gridDim.x * 2;
  for (int n = blockIdx.x*2 + h2; n < N; n += step){
    float wn = wsrc[n];
    uint_t u = hneib[(size_t)n*128 + p];
    a0 += wn * b2f_lo(u);
    a1 += wn * b2f_hi(u);
  }
  pr[h2*256 + 2*p]     = a0;
  pr[h2*256 + 2*p + 1] = a1;
  __syncthreads();
  float v = pr[t] + pr[256 + t];
  int pp = t >> 1;
  int d = (pp >> 5)*64 + 2*(pp & 31) + (t & 1);
  atomicAdd(&acc256[d], v);
}

// ---------------- finalize
__global__ __launch_bounds__(256) void k_finalize(const float* __restrict__ acc256,
    const float* __restrict__ accFrac, const float* __restrict__ W2,
    const float* __restrict__ frw, const float* __restrict__ frf,
    const float* __restrict__ fc2, float* __restrict__ out, float invN)
{
  __shared__ float mh[256], nei[64], g[384], mm[192], hfrac[64];
  int t = threadIdx.x;
  mh[t] = acc256[t] * invN;
  for (int i = t; i < 384; i += 256) g[i] = accFrac[i] * invN;
  __syncthreads();
  if (t < 64){
    float s = 0.f;
    for (int k = 0; k < 256; k++) s += W2[t*256 + k] * mh[k];
    nei[t] = s;
  }
  for (int i = t; i < 192; i += 256){
    int s = i >> 6, d = i & 63;
    const float* w = frw + (size_t)(s*64 + d)*128;
    const float* gs = g + s*128;
    float sum = 0.f;
    for (int k = 0; k < 128; k++) sum += gs[k]*w[k];
    mm[i] = sum;
  }
  __syncthreads();
  if (t < 64){
    float s = 0.f;
    for (int k = 0; k < 192; k++) s += mm[k]*frf[t*192 + k];
    hfrac[t] = s;
  }
  __syncthreads();
  if (t < 64){
    float o = 0.f;
    for (int k = 0; k < 64; k++)
      o += fc2[t*128 + k]*nei[k] + fc2[t*128 + 64 + k]*hfrac[k];
    out[t] = o;
  }
}

extern "C" void kernel_launch(void* const* d_in, const int* in_sizes, int n_in,
                              void* d_out, int out_size, void* d_ws, size_t ws_size,
                              hipStream_t stream)
{
  const float* h    = (const float*)d_in[0];
  const int*   srcI = (const int*)  d_in[1];
  const int*   dstI = (const int*)  d_in[2];
  const int*   fcm  = (const int*)  d_in[3];
  const float* l1fc = (const float*)d_in[4];
  const float* l1at = (const float*)d_in[5];
  const float* l2fc = (const float*)d_in[6];
  const float* l2at = (const float*)d_in[7];
  const float* frw  = (const float*)d_in[8];
  const float* frf  = (const float*)d_in[9];
  const float* fc2  = (const float*)d_in[10];
  float* out = (float*)d_out;
  (void)n_in; (void)out_size; (void)ws_size;

  const int N = in_sizes[0] / 128;
  const int E = in_sizes[1];
  const int B = (N + 256) / 256;     // ceil((N+1)/256) so rowptr[N] is covered
  const int PAD = B * 256;

  char* w = (char*)d_ws;
  size_t off = 0;
  auto alloc = [&](size_t bytes) -> char* {
    char* p = w + off; off = (off + bytes + 255) & ~(size_t)255; return p;
  };
  uint_t* z8    = (uint_t*)alloc((size_t)N*64*4);    // 25.6 MB fp8 z
  uint_t* hneib = (uint_t*)alloc((size_t)N*128*4);   // 51.2 MB packed bf16 hnei
  float* s1s  = (float*)alloc((size_t)N*4*4);
  float* s1d  = (float*)alloc((size_t)N*4*4);
  float* s2s  = (float*)alloc((size_t)N*4);
  float* s2d  = (float*)alloc((size_t)N*4);
  // ---- zeroed region (one memset): deg, wsrc, acc256, accFrac
  int*   deg     = (int*)  alloc((size_t)PAD*4);
  float* wsrc    = (float*)alloc((size_t)N*4);
  float* acc256  = (float*)alloc(256*4);
  float* accFrac = (float*)alloc(384*4);
  const size_t zbytes = (size_t)((char*)accFrac + 384*4 - (char*)deg);
  // ---- rest
  int*   rowptr = (int*)alloc((size_t)PAD*4);
  int*   cursor = (int*)alloc((size_t)PAD*4);
  int*   part   = (int*)alloc(512*4);
  int*   csr    = (int*)alloc((size_t)E*4);
  ushort_t* w1bp = (ushort_t*)alloc(34816*2);   // 16 z-tiles + 1 score tile
  float* v2     = (float*)alloc(512*4);

  hipMemsetAsync(deg, 0, zbytes, stream);

  hipLaunchKernelGGL(k_prep,  dim3(130 + 512), dim3(256), 0, stream,
                     l1fc, l2fc, l1at, l2at, dstI, E, w1bp, v2, deg);
  hipLaunchKernelGGL(k_scan1, dim3(B),   dim3(256), 0, stream, deg, part);
  hipLaunchKernelGGL(k_scan2, dim3(1),   dim3(512), 0, stream, part, B);
  hipLaunchKernelGGL(k_scan3, dim3(B),   dim3(256), 0, stream, deg, part, rowptr, cursor);

  const int Gg = (N + 127) / 128;
  const int Gs = (E + 511) / 512;
  const int Gf = 512;
  hipLaunchKernelGGL(k_mega,  dim3(Gg + Gs + Gf), dim3(512), 0, stream,
                     h, w1bp, z8, s1s, s1d, N,
                     srcI, dstI, cursor, csr, E, Gg, Gs,
                     fcm, accFrac);
  hipLaunchKernelGGL(k_gat1,  dim3((N+3)/4), dim3(256), 0, stream,
                     z8, s1s, s1d, rowptr, csr, v2, hneib, s2s, s2d, N);
  hipLaunchKernelGGL(k_aw2,   dim3((N+3)/4), dim3(256), 0, stream,
                     s2s, s2d, rowptr, csr, wsrc, N);
  hipLaunchKernelGGL(k_hsum,  dim3(608),     dim3(256), 0, stream,
                     hneib, wsrc, acc256, N);
  hipLaunchKernelGGL(k_finalize, dim3(1),    dim3(256), 0, stream,
                     acc256, accFrac, l2fc, frw, frf, fc2, out, 1.0f/(float)N);
}

// Round 14
// 532.403 us; speedup vs baseline: 1.4247x; 1.1546x over previous
//
#include <hip/hip_runtime.h>
#include <math.h>

// GAT pipeline. Layer2 collapsed (w_s = Σ α over src edges); z fp8 e4m3; MFMA
// GEMM1 with f32 score tile. Mega-kernel (gemm+scatter+frac) with block-role
// STRIPING (coprime-stride permutation of blockIdx) and half-pass GEMM
// (36.9KB LDS, c[9] accumulators). R13 bug: half-1 staging offset was 1024
// uint4 (mid-tile-4) instead of 2048 (tile 8) — fixed.

#define CAP 128

typedef unsigned int  uint_t;
typedef unsigned short ushort_t;
typedef __attribute__((ext_vector_type(8))) short short8;
typedef __attribute__((ext_vector_type(4))) float floatx4;
typedef __attribute__((ext_vector_type(2))) float floatx2;

__device__ __forceinline__ float wred_sum(float v){
#pragma unroll
  for (int o = 1; o < 64; o <<= 1) v += __shfl_xor(v, o, 64);
  return v;
}
__device__ __forceinline__ float lrelu(float x){ return x >= 0.f ? x : 0.01f*x; }
__device__ __forceinline__ ushort_t f2b(float f){
  uint_t u = __float_as_uint(f);
  u = (u + 0x7FFFu + ((u >> 16) & 1u)) >> 16;   // RNE
  return (ushort_t)u;
}
__device__ __forceinline__ float b2f_lo(uint_t w){ return __uint_as_float(w << 16); }
__device__ __forceinline__ float b2f_hi(uint_t w){ return __uint_as_float(w & 0xFFFF0000u); }

// ---------------- prep: W1 pack (PERMUTED tile order: m<2 -> 0..7, m>=2 -> 8..15,
// score=16), score tile, v2, + hist. Roles by blockIdx.
__global__ void k_prep(const float* __restrict__ W1, const float* __restrict__ W2,
                       const float* __restrict__ a1, const float* __restrict__ a2,
                       const int* __restrict__ dstI, int E,
                       ushort_t* __restrict__ w1bp, float* __restrict__ v2,
                       int* __restrict__ deg){
  __shared__ float v[8][128];
  const int bx = blockIdx.x, t = threadIdx.x;
  if (bx < 128){
    int idx = bx*256 + t;
    int j = idx & 7, lane = (idx >> 3) & 63, ks = (idx >> 9) & 3, tt = idx >> 11;
    int n = tt*16 + (lane & 15), k = ks*32 + (lane >> 4)*8 + j;
    int hh = tt >> 2, m = tt & 3;
    int pt = (m < 2) ? (hh*2 + m) : (8 + hh*2 + (m - 2));
    w1bp[((pt*4 + ks)*64 + lane)*8 + j] = f2b(W1[n*128 + k]);
  } else if (bx == 128){
    for (int o = t; o < 1024; o += 256){
      int col = o >> 7, k = o & 127, hh = col & 3, off = (col >> 2)*64;
      float s = 0.f;
      for (int n = 0; n < 64; n++) s += a1[hh*128 + off + n] * W1[(hh*64 + n)*128 + k];
      v[col][k] = s;
    }
    __syncthreads();
    for (int idx = t; idx < 2048; idx += 256){
      int j = idx & 7, lane = (idx >> 3) & 63, ks = idx >> 9;
      int col = lane & 15, k = ks*32 + (lane >> 4)*8 + j;
      w1bp[32768 + idx] = (col < 8) ? f2b(v[col][k]) : (ushort_t)0;   // packed tile 16
    }
  } else if (bx == 129){
    float s0 = 0.f, s1 = 0.f;
    for (int j = 0; j < 64; j++){
      float wjk = W2[j*256 + t];
      s0 += wjk * a2[j];
      s1 += wjk * a2[64 + j];
    }
    v2[t] = s0; v2[256 + t] = s1;
  } else {
    const int nb = gridDim.x - 130;
    for (int i = (bx-130)*256 + t; i < E; i += nb*256)
      atomicAdd(&deg[dstI[i]], 1);
  }
}

// ---------------- scans
__global__ __launch_bounds__(256) void k_scan1(const int* __restrict__ deg, int* __restrict__ part){
  __shared__ int tmp[256];
  int t = threadIdx.x;
  tmp[t] = deg[blockIdx.x*256 + t];
  __syncthreads();
  for (int off = 128; off > 0; off >>= 1){
    if (t < off) tmp[t] += tmp[t+off];
    __syncthreads();
  }
  if (t == 0) part[blockIdx.x] = tmp[0];
}
__global__ __launch_bounds__(512) void k_scan2(int* __restrict__ part, int B){
  __shared__ int tmp[512];
  int t = threadIdx.x;
  int v = (t < B) ? part[t] : 0;
  tmp[t] = v; __syncthreads();
  for (int off = 1; off < 512; off <<= 1){
    int x = (t >= off) ? tmp[t-off] : 0;
    __syncthreads();
    tmp[t] += x;
    __syncthreads();
  }
  if (t < B) part[t] = tmp[t] - v;   // exclusive
}
__global__ __launch_bounds__(256) void k_scan3(const int* __restrict__ deg, const int* __restrict__ part,
    int* __restrict__ rowptr, int* __restrict__ cursor){
  __shared__ int tmp[256];
  int t = threadIdx.x, i = blockIdx.x*256 + t;
  int v = deg[i];
  tmp[t] = v; __syncthreads();
  for (int off = 1; off < 256; off <<= 1){
    int x = (t >= off) ? tmp[t-off] : 0;
    __syncthreads();
    tmp[t] += x;
    __syncthreads();
  }
  int excl = tmp[t] - v + part[blockIdx.x];
  rowptr[i] = excl; cursor[i] = excl;
}

// ---------------- MEGA (striped roles): gemm + scatter + frac
__global__ __launch_bounds__(512) void k_mega(const float* __restrict__ h,
    const ushort_t* __restrict__ w1bp,
    uint_t* __restrict__ z8, float* __restrict__ s1s, float* __restrict__ s1d, int N,
    const int* __restrict__ srcI, const int* __restrict__ dstI,
    int* __restrict__ cursor, int* __restrict__ csr, int E,
    int Gg, int Gs, int G, int step,
    const int* __restrict__ fcm, float* __restrict__ accFrac)
{
  static __shared__ __align__(16) char smem[36864];
  const int tid = threadIdx.x;
  const int id = (int)(((unsigned long long)blockIdx.x * (unsigned)step) % (unsigned)G);
  if (id < Gg){
    // ---- GEMM role: 128 rows/block, two half-passes (packed tiles 0..7, 8..16)
    ushort_t* ldsB = (ushort_t*)smem;
    const int wave = tid >> 6, lane = tid & 63;
    const int quad = lane >> 4, l16 = lane & 15;
    const int row0 = id*128 + wave*16;
    const bool act = row0 < N;
    const int ar = act ? ((row0 + l16 < N) ? (row0 + l16) : (N - 1)) : 0;
#pragma unroll
    for (int half = 0; half < 2; half++){
      __syncthreads();
      {
        const int cnt = half ? 2304 : 2048;                 // uint4 count
        const uint4* src = (const uint4*)w1bp + (half ? 2048 : 0);   // tile 8 = ushort 16384 = uint4 2048
        uint4* dst = (uint4*)ldsB;
        for (int i = tid; i < cnt; i += 512) dst[i] = src[i];
      }
      __syncthreads();
      if (!act) continue;
      const int nt = half ? 9 : 8;
      floatx4 c[9];
#pragma unroll
      for (int i = 0; i < 9; i++) c[i] = (floatx4){0.f,0.f,0.f,0.f};
#pragma unroll
      for (int ks = 0; ks < 4; ks++){
        const float* ap = &h[(size_t)ar*128 + ks*32 + quad*8];
        float4 v0 = *(const float4*)ap;
        float4 v1 = *(const float4*)(ap + 4);
        float vv[8] = {v0.x,v0.y,v0.z,v0.w,v1.x,v1.y,v1.z,v1.w};
        short8 ahi, alo;
#pragma unroll
        for (int j = 0; j < 8; j++){
          ushort_t hb = f2b(vv[j]);
          float hf = __uint_as_float((uint_t)hb << 16);
          ahi[j] = (short)hb;
          alo[j] = (short)f2b(vv[j] - hf);
        }
        for (int i = 0; i < nt; i++){
          short8 b = *(const short8*)&ldsB[(size_t)((i*4 + ks)*64 + lane)*8];
          c[i] = __builtin_amdgcn_mfma_f32_16x16x32_bf16(ahi, b, c[i], 0, 0, 0);
        }
        if (half){
          short8 b = *(const short8*)&ldsB[(size_t)((8*4 + ks)*64 + lane)*8];
          c[8] = __builtin_amdgcn_mfma_f32_16x16x32_bf16(alo, b, c[8], 0, 0, 0);
        }
      }
      // epilogue: local tile i = hh*2 + (m - m0); cols = hh*64 + m*16 + l16
      const int m0 = half ? 2 : 0;
#pragma unroll
      for (int i = 0; i < 4; i++){
        const int r = row0 + quad*4 + i;
        if (r >= N) continue;
#pragma unroll
        for (int dm = 0; dm < 2; dm++){
          int u = 0;
          u = __builtin_amdgcn_cvt_pk_fp8_f32(c[0*2+dm][i], c[1*2+dm][i], u, false);
          u = __builtin_amdgcn_cvt_pk_fp8_f32(c[2*2+dm][i], c[3*2+dm][i], u, true);
          z8[(size_t)r*64 + (m0+dm)*16 + l16] = (uint_t)u;
        }
        if (half){
          const float sv = c[8][i];
          if (l16 < 4) s1s[r*4 + l16] = sv;
          else if (l16 < 8) s1d[r*4 + (l16 - 4)] = sv;
        }
      }
    }
  } else if (id < Gg + Gs){
    // ---- scatter role
    const int i = (id - Gg)*512 + tid;
    if (i < E){
      int p = atomicAdd(&cursor[dstI[i]], 1);
      csr[p] = srcI[i];
    }
  } else {
    // ---- frac role (16 node-streams/block)
    float (*red)[384] = (float(*)[384])smem;
    const int wave = tid >> 6, lane = tid & 63;
    const int g = lane >> 5, li = lane & 31;
    const int Gf = G - Gg - Gs;
    const int stream0 = (id - Gg - Gs)*16 + wave*2 + g;
    const int step16 = Gf * 16;
    float4 a0 = {0,0,0,0}, a1 = {0,0,0,0}, a2 = {0,0,0,0};
    for (int n = stream0; n < N; n += step16){
      int i0 = fcm[n*3], i1 = fcm[n*3+1], i2 = fcm[n*3+2];
      float4 v0 = *(const float4*)&h[(size_t)i0*128 + li*4];
      float4 v1 = *(const float4*)&h[(size_t)i1*128 + li*4];
      float4 v2 = *(const float4*)&h[(size_t)i2*128 + li*4];
      a0.x += v0.x; a0.y += v0.y; a0.z += v0.z; a0.w += v0.w;
      a1.x += v1.x; a1.y += v1.y; a1.z += v1.z; a1.w += v1.w;
      a2.x += v2.x; a2.y += v2.y; a2.z += v2.z; a2.w += v2.w;
    }
    const int w16 = wave*2 + g;
    *(float4*)&red[w16][0*128 + li*4] = a0;
    *(float4*)&red[w16][1*128 + li*4] = a1;
    *(float4*)&red[w16][2*128 + li*4] = a2;
    __syncthreads();
    for (int i = tid; i < 384; i += 512){
      float v = 0.f;
#pragma unroll
      for (int w = 0; w < 16; w++) v += red[w][i];
      atomicAdd(&accFrac[i], v);
    }
  }
}

// ---------------- layer1 GAT aggregation + ELU -> hneib bf16 + fused layer2 scores
__global__ __launch_bounds__(256) void k_gat1(
    const uint_t* __restrict__ z8, const float* __restrict__ s1src, const float* __restrict__ s1dst,
    const int* __restrict__ rowptr, const int* __restrict__ csr, const float* __restrict__ v2,
    uint_t* __restrict__ hneib, float* __restrict__ s2s, float* __restrict__ s2d, int N)
{
  __shared__ int   sbuf[4][CAP];
  __shared__ __align__(16) float4 ebuf[4][CAP];
  __shared__ float v2s[512];
  const int tid = threadIdx.x;
  v2s[tid] = v2[tid];
  v2s[tid + 256] = v2[tid + 256];
  __syncthreads();
  const int wave = tid >> 6, lane = tid & 63;
  const int dst = blockIdx.x*4 + wave;
  if (dst >= N) return;
  const int beg = rowptr[dst];
  const int deg = rowptr[dst+1] - beg;
  const float4 sd = *(const float4*)&s1dst[dst*4];
  float t0=0.f,t1=0.f,t2=0.f,t3=0.f;
  for (int j = lane; j < deg; j += 64){
    int s = csr[beg+j];
    float4 sv = *(const float4*)&s1src[s*4];
    float4 a;
    a.x = __expf(lrelu(sv.x+sd.x)); a.y = __expf(lrelu(sv.y+sd.y));
    a.z = __expf(lrelu(sv.z+sd.z)); a.w = __expf(lrelu(sv.w+sd.w));
    if (j < CAP){ sbuf[wave][j] = s; ebuf[wave][j] = a; }
    t0 += a.x; t1 += a.y; t2 += a.z; t3 += a.w;
  }
  const float inv[4] = {1.f/wred_sum(t0), 1.f/wred_sum(t1), 1.f/wred_sum(t2), 1.f/wred_sum(t3)};
  const int eh = lane >> 5, li = lane & 31;
  float acc[2][4] = {};
  int jj = 0;
  if (deg <= CAP){
    for (; jj + 2 <= deg; jj += 2){
      const int j = jj + eh;
      int s = sbuf[wave][j]; float4 al = ebuf[wave][j];
      uint2 u = *((const uint2*)(z8 + (size_t)s*64) + li);
      floatx2 p0 = __builtin_amdgcn_cvt_pk_f32_fp8(u.x, false);
      floatx2 p1 = __builtin_amdgcn_cvt_pk_f32_fp8(u.x, true);
      floatx2 p2 = __builtin_amdgcn_cvt_pk_f32_fp8(u.y, false);
      floatx2 p3 = __builtin_amdgcn_cvt_pk_f32_fp8(u.y, true);
      acc[0][0] += al.x * p0.x;
      acc[0][1] += al.y * p0.y;
      acc[0][2] += al.z * p1.x;
      acc[0][3] += al.w * p1.y;
      acc[1][0] += al.x * p2.x;
      acc[1][1] += al.y * p2.y;
      acc[1][2] += al.z * p3.x;
      acc[1][3] += al.w * p3.y;
    }
    if (jj < deg && eh == 0){
      int s = sbuf[wave][jj]; float4 al = ebuf[wave][jj];
      uint2 u = *((const uint2*)(z8 + (size_t)s*64) + li);
      floatx2 p0 = __builtin_amdgcn_cvt_pk_f32_fp8(u.x, false);
      floatx2 p1 = __builtin_amdgcn_cvt_pk_f32_fp8(u.x, true);
      floatx2 p2 = __builtin_amdgcn_cvt_pk_f32_fp8(u.y, false);
      floatx2 p3 = __builtin_amdgcn_cvt_pk_f32_fp8(u.y, true);
      acc[0][0] += al.x * p0.x;
      acc[0][1] += al.y * p0.y;
      acc[0][2] += al.z * p1.x;
      acc[0][3] += al.w * p1.y;
      acc[1][0] += al.x * p2.x;
      acc[1][1] += al.y * p2.y;
      acc[1][2] += al.z * p3.x;
      acc[1][3] += al.w * p3.y;
    }
  } else {
    for (; jj < deg; jj += 2){
      const int j = jj + eh;
      const bool v = j < deg;
      const int jc = v ? j : jj;
      int s; float4 al;
      if (jc < CAP){ s = sbuf[wave][jc]; al = ebuf[wave][jc]; }
      else {
        s = csr[beg+jc];
        float4 sv = *(const float4*)&s1src[s*4];
        al.x = __expf(lrelu(sv.x+sd.x)); al.y = __expf(lrelu(sv.y+sd.y));
        al.z = __expf(lrelu(sv.z+sd.z)); al.w = __expf(lrelu(sv.w+sd.w));
      }
      if (!v){ al.x=0.f; al.y=0.f; al.z=0.f; al.w=0.f; }
      uint2 u = *((const uint2*)(z8 + (size_t)s*64) + li);
      floatx2 p0 = __builtin_amdgcn_cvt_pk_f32_fp8(u.x, false);
      floatx2 p1 = __builtin_amdgcn_cvt_pk_f32_fp8(u.x, true);
      floatx2 p2 = __builtin_amdgcn_cvt_pk_f32_fp8(u.y, false);
      floatx2 p3 = __builtin_amdgcn_cvt_pk_f32_fp8(u.y, true);
      acc[0][0] += al.x * p0.x;
      acc[0][1] += al.y * p0.y;
      acc[0][2] += al.z * p1.x;
      acc[0][3] += al.w * p1.y;
      acc[1][0] += al.x * p2.x;
      acc[1][1] += al.y * p2.y;
      acc[1][2] += al.z * p3.x;
      acc[1][3] += al.w * p3.y;
    }
  }
#pragma unroll
  for (int k = 0; k < 2; k++)
#pragma unroll
    for (int hh = 0; hh < 4; hh++) acc[k][hh] += __shfl_xor(acc[k][hh], 32, 64);
  const float* vv = &v2s[eh*256];
  float p = 0.f;
#pragma unroll
  for (int hh = 0; hh < 4; hh++){
    float e0 = acc[0][hh]*inv[hh]; e0 = e0 > 0.f ? e0 : expm1f(e0);
    float e1 = acc[1][hh]*inv[hh]; e1 = e1 > 0.f ? e1 : expm1f(e1);
    p += e0 * vv[hh*64 + 2*li] + e1 * vv[hh*64 + 2*li + 1];
    if (eh == 0)
      hneib[(size_t)dst*128 + hh*32 + li] = (uint_t)f2b(e0) | ((uint_t)f2b(e1) << 16);
  }
#pragma unroll
  for (int o = 1; o < 32; o <<= 1) p += __shfl_xor(p, o, 64);
  if (lane == 0)  s2s[dst] = p;
  if (lane == 32) s2d[dst] = p;
}

// ---------------- layer2 alpha-weights: wave per dst over CSR; one atomic per edge
__global__ __launch_bounds__(256) void k_aw2(
    const float* __restrict__ s2s, const float* __restrict__ s2d,
    const int* __restrict__ rowptr, const int* __restrict__ csr,
    float* __restrict__ wsrc, int N)
{
  __shared__ int   sbuf[4][CAP];
  __shared__ float ebuf[4][CAP];
  const int wave = threadIdx.x >> 6, lane = threadIdx.x & 63;
  const int dst = blockIdx.x*4 + wave;
  if (dst >= N) return;
  const int beg = rowptr[dst], deg = rowptr[dst+1] - beg;
  const float sd = s2d[dst];
  float ts = 0.f;
  for (int j = lane; j < deg; j += 64){
    int s = csr[beg+j];
    float a = __expf(lrelu(s2s[s] + sd));
    if (j < CAP){ sbuf[wave][j] = s; ebuf[wave][j] = a; }
    ts += a;
  }
  const float inv = 1.f/wred_sum(ts);
  for (int j = lane; j < deg; j += 64){
    int s; float a;
    if (j < CAP){ s = sbuf[wave][j]; a = ebuf[wave][j]; }
    else { s = csr[beg+j]; a = __expf(lrelu(s2s[s] + sd)); }
    atomicAdd(&wsrc[s], a * inv);
  }
}

// ---------------- weighted hnei sum (coalesced)
__global__ __launch_bounds__(256) void k_hsum(const uint_t* __restrict__ hneib,
    const float* __restrict__ wsrc, float* __restrict__ acc256, int N)
{
  __shared__ float pr[512];
  const int t = threadIdx.x;
  const int h2 = t >> 7, p = t & 127;
  float a0 = 0.f, a1 = 0.f;
  const int step = gridDim.x * 2;
  for (int n = blockIdx.x*2 + h2; n < N; n += step){
    float wn = wsrc[n];
    uint_t u = hneib[(size_t)n*128 + p];
    a0 += wn * b2f_lo(u);
    a1 += wn * b2f_hi(u);
  }
  pr[h2*256 + 2*p]     = a0;
  pr[h2*256 + 2*p + 1] = a1;
  __syncthreads();
  float v = pr[t] + pr[256 + t];
  int pp = t >> 1;
  int d = (pp >> 5)*64 + 2*(pp & 31) + (t & 1);
  atomicAdd(&acc256[d], v);
}

// ---------------- finalize
__global__ __launch_bounds__(256) void k_finalize(const float* __restrict__ acc256,
    const float* __restrict__ accFrac, const float* __restrict__ W2,
    const float* __restrict__ frw, const float* __restrict__ frf,
    const float* __restrict__ fc2, float* __restrict__ out, float invN)
{
  __shared__ float mh[256], nei[64], g[384], mm[192], hfrac[64];
  int t = threadIdx.x;
  mh[t] = acc256[t] * invN;
  for (int i = t; i < 384; i += 256) g[i] = accFrac[i] * invN;
  __syncthreads();
  if (t < 64){
    float s = 0.f;
    for (int k = 0; k < 256; k++) s += W2[t*256 + k] * mh[k];
    nei[t] = s;
  }
  for (int i = t; i < 192; i += 256){
    int s = i >> 6, d = i & 63;
    const float* w = frw + (size_t)(s*64 + d)*128;
    const float* gs = g + s*128;
    float sum = 0.f;
    for (int k = 0; k < 128; k++) sum += gs[k]*w[k];
    mm[i] = sum;
  }
  __syncthreads();
  if (t < 64){
    float s = 0.f;
    for (int k = 0; k < 192; k++) s += mm[k]*frf[t*192 + k];
    hfrac[t] = s;
  }
  __syncthreads();
  if (t < 64){
    float o = 0.f;
    for (int k = 0; k < 64; k++)
      o += fc2[t*128 + k]*nei[k] + fc2[t*128 + 64 + k]*hfrac[k];
    out[t] = o;
  }
}

extern "C" void kernel_launch(void* const* d_in, const int* in_sizes, int n_in,
                              void* d_out, int out_size, void* d_ws, size_t ws_size,
                              hipStream_t stream)
{
  const float* h    = (const float*)d_in[0];
  const int*   srcI = (const int*)  d_in[1];
  const int*   dstI = (const int*)  d_in[2];
  const int*   fcm  = (const int*)  d_in[3];
  const float* l1fc = (const float*)d_in[4];
  const float* l1at = (const float*)d_in[5];
  const float* l2fc = (const float*)d_in[6];
  const float* l2at = (const float*)d_in[7];
  const float* frw  = (const float*)d_in[8];
  const float* frf  = (const float*)d_in[9];
  const float* fc2  = (const float*)d_in[10];
  float* out = (float*)d_out;
  (void)n_in; (void)out_size; (void)ws_size;

  const int N = in_sizes[0] / 128;
  const int E = in_sizes[1];
  const int B = (N + 256) / 256;     // ceil((N+1)/256) so rowptr[N] is covered
  const int PAD = B * 256;

  char* w = (char*)d_ws;
  size_t off = 0;
  auto alloc = [&](size_t bytes) -> char* {
    char* p = w + off; off = (off + bytes + 255) & ~(size_t)255; return p;
  };
  uint_t* z8    = (uint_t*)alloc((size_t)N*64*4);    // 25.6 MB fp8 z
  uint_t* hneib = (uint_t*)alloc((size_t)N*128*4);   // 51.2 MB packed bf16 hnei
  float* s1s  = (float*)alloc((size_t)N*4*4);
  float* s1d  = (float*)alloc((size_t)N*4*4);
  float* s2s  = (float*)alloc((size_t)N*4);
  float* s2d  = (float*)alloc((size_t)N*4);
  // ---- zeroed region (one memset): deg, wsrc, acc256, accFrac
  int*   deg     = (int*)  alloc((size_t)PAD*4);
  float* wsrc    = (float*)alloc((size_t)N*4);
  float* acc256  = (float*)alloc(256*4);
  float* accFrac = (float*)alloc(384*4);
  const size_t zbytes = (size_t)((char*)accFrac + 384*4 - (char*)deg);
  // ---- rest
  int*   rowptr = (int*)alloc((size_t)PAD*4);
  int*   cursor = (int*)alloc((size_t)PAD*4);
  int*   part   = (int*)alloc(512*4);
  int*   csr    = (int*)alloc((size_t)E*4);
  ushort_t* w1bp = (ushort_t*)alloc(34816*2);   // 16 z-tiles (permuted) + score tile
  float* v2     = (float*)alloc(512*4);

  hipMemsetAsync(deg, 0, zbytes, stream);

  hipLaunchKernelGGL(k_prep,  dim3(130 + 512), dim3(256), 0, stream,
                     l1fc, l2fc, l1at, l2at, dstI, E, w1bp, v2, deg);
  hipLaunchKernelGGL(k_scan1, dim3(B),   dim3(256), 0, stream, deg, part);
  hipLaunchKernelGGL(k_scan2, dim3(1),   dim3(512), 0, stream, part, B);
  hipLaunchKernelGGL(k_scan3, dim3(B),   dim3(256), 0, stream, deg, part, rowptr, cursor);

  const int Gg = (N + 127) / 128;
  const int Gs = (E + 511) / 512;
  const int Gf = 512;
  const int G  = Gg + Gs + Gf;
  int step = (int)(G * 0.618) | 1;
  auto gcd = [](int a, int b){ while (b){ int t = a % b; a = b; b = t; } return a; };
  while (gcd(step, G) != 1) step += 2;

  hipLaunchKernelGGL(k_mega,  dim3(G), dim3(512), 0, stream,
                     h, w1bp, z8, s1s, s1d, N,
                     srcI, dstI, cursor, csr, E, Gg, Gs, G, step,
                     fcm, accFrac);
  hipLaunchKernelGGL(k_gat1,  dim3((N+3)/4), dim3(256), 0, stream,
                     z8, s1s, s1d, rowptr, csr, v2, hneib, s2s, s2d, N);
  hipLaunchKernelGGL(k_aw2,   dim3((N+3)/4), dim3(256), 0, stream,
                     s2s, s2d, rowptr, csr, wsrc, N);
  hipLaunchKernelGGL(k_hsum,  dim3(608),     dim3(256), 0, stream,
                     hneib, wsrc, acc256, N);
  hipLaunchKernelGGL(k_finalize, dim3(1),    dim3(256), 0, stream,
                     acc256, accFrac, l2fc, frw, frf, fc2, out, 1.0f/(float)N);
}